// Round 3
// baseline (239.691 us; speedup 1.0000x reference)
//
#include <hip/hip_runtime.h>
#include <hip/hip_bf16.h>
#include <math.h>

// Problem constants
#define BB 2
#define SS 1024
#define DD 768
#define HH 12
#define DHH 64
#define MM 64
#define DFF 3072
#define BS (BB*SS)          // 2048 rows
#define EPS_LN 1e-5f
#define EPS_PHI 1e-6f
#define CC 64               // scan chunk length
#define NC (SS/CC)          // 16 chunks
#define NQ 3840             // q,k,v (2304) + proj_q (768) + proj_k (768)
#define PQOFF 2304
#define PKOFF 3072
#define VOFF  1536

typedef __hip_bfloat16 bf16;
using v8s = __attribute__((ext_vector_type(8))) short;   // 8 bf16 (MFMA A/B frag)
using v4f = __attribute__((ext_vector_type(4))) float;   // MFMA C/D frag
struct b4 { bf16 v[4]; };                                // 8B packed bf16 quad

// Direct global->LDS 16B async copy (width=16).
// LDS dest is wave-uniform base + lane*16; global src is per-lane.
typedef const __attribute__((address_space(1))) void ga_void;
typedef __attribute__((address_space(3))) void ls_void;
__device__ __forceinline__ void gload16(const void* g, void* l) {
    __builtin_amdgcn_global_load_lds((ga_void*)g, (ls_void*)l, 16, 0, 0);
}

// ---------------------------------------------------------------------------
// All four weight transposes in ONE dispatch.
// ---------------------------------------------------------------------------
__global__ __launch_bounds__(256) void transpose_all_kernel(const float* __restrict__ w_attn,
                                                            const float* __restrict__ w_proj,
                                                            const float* __restrict__ w_fc,
                                                            const float* __restrict__ w_out,
                                                            bf16* __restrict__ wext_t,
                                                            bf16* __restrict__ wproj_t,
                                                            bf16* __restrict__ wfc_t,
                                                            bf16* __restrict__ wout_t) {
    int bid = blockIdx.x;
    const float* in; bf16* outp; int K, N, xt, yt;
    if (bid < 1728)      { in = w_attn; outp = wext_t;  K = 768;  N = 2304; xt = bid % 72;          yt = bid / 72; }
    else if (bid < 2304) { int b = bid - 1728; in = w_proj; outp = wproj_t; K = 768;  N = 768;  xt = b % 24; yt = b / 24; }
    else if (bid < 4608) { int b = bid - 2304; in = w_fc;   outp = wfc_t;   K = 768;  N = 3072; xt = b % 96; yt = b / 96; }
    else                 { int b = bid - 4608; in = w_out;  outp = wout_t;  K = 3072; N = 768;  xt = b % 24; yt = b / 24; }
    __shared__ float t[32][33];
    int tx = threadIdx.x & 31, ty = threadIdx.x >> 5;    // 32 x 8
    int n0 = xt * 32, k0 = yt * 32;
    #pragma unroll
    for (int i = ty; i < 32; i += 8)
        t[i][tx] = in[(size_t)(k0 + i) * N + n0 + tx];
    __syncthreads();
    #pragma unroll
    for (int i = ty; i < 32; i += 8)
        outp[(size_t)(n0 + i) * K + k0 + tx] = __float2bfloat16(t[tx][i]);
}

// ---------------------------------------------------------------------------
// Fused FAVOR+ projection weights (cols 2304..3839 of W_ext) + bias_ext.
// ---------------------------------------------------------------------------
__global__ __launch_bounds__(256) void fuse_feat_kernel(const float* __restrict__ w_attn,
                                                        const float* __restrict__ b_attn,
                                                        const float* __restrict__ wfeat,
                                                        bf16* __restrict__ bt_ext,
                                                        float* __restrict__ bias_ext) {
    __shared__ float wfT[64][65];   // wfT[d][m] = scale*wf[m][d]
    __shared__ float Wt[64][65];    // Wt[j][d]
    int t = threadIdx.x;
    int j0 = blockIdx.x * 64, h = blockIdx.y, isK = blockIdx.z;
    int base = isK * DD + h * DHH;
    const float scale = 0.35355339059327373f;  // 64^-0.25
    #pragma unroll
    for (int it = 0; it < 16; it++) {
        int idx = it * 256 + t;
        int m = idx >> 6, d = idx & 63;
        wfT[d][m] = scale * wfeat[m * DHH + d];
        Wt[idx >> 6][idx & 63] = w_attn[(size_t)(j0 + (idx >> 6)) * (3 * DD) + base + (idx & 63)];
    }
    __syncthreads();
    int jl = t & 63, mg = (t >> 6) * 16;
    for (int m = mg; m < mg + 16; m++) {
        float acc = 0.f;
        #pragma unroll 8
        for (int d = 0; d < 64; d++) acc += wfT[d][m] * Wt[jl][d];
        bt_ext[(size_t)(PQOFF + isK * DD + h * DHH + m) * DD + j0 + jl] = __float2bfloat16(acc);
    }
    if (blockIdx.x == 0 && t < 64) {
        float accb = 0.f;
        #pragma unroll 8
        for (int d = 0; d < 64; d++) accb += wfT[d][t] * b_attn[base + d];
        bias_ext[PQOFF + isK * DD + h * DHH + t] = accb;
    }
}

// ---------------------------------------------------------------------------
// LayerNorm: one block per row, 256 threads; f32 in -> bf16 out.
// ---------------------------------------------------------------------------
__global__ __launch_bounds__(256) void ln_kernel(const float* __restrict__ x,
                                                 const float* __restrict__ g,
                                                 const float* __restrict__ bta,
                                                 bf16* __restrict__ out) {
    int row = blockIdx.x;
    int t = threadIdx.x;
    const float* xr = x + (size_t)row * DD;
    float v0 = xr[t], v1 = xr[t + 256], v2 = xr[t + 512];
    float s = v0 + v1 + v2;
    float s2 = v0 * v0 + v1 * v1 + v2 * v2;
    #pragma unroll
    for (int off = 32; off > 0; off >>= 1) {
        s  += __shfl_xor(s,  off, 64);
        s2 += __shfl_xor(s2, off, 64);
    }
    __shared__ float ls[4], ls2[4];
    if ((t & 63) == 0) { ls[t >> 6] = s; ls2[t >> 6] = s2; }
    __syncthreads();
    s  = ls[0] + ls[1] + ls[2] + ls[3];
    s2 = ls2[0] + ls2[1] + ls2[2] + ls2[3];
    float mu  = s * (1.0f / DD);
    float var = s2 * (1.0f / DD) - mu * mu;
    float r = rsqrtf(var + EPS_LN);
    bf16* orow = out + (size_t)row * DD;
    orow[t]       = __float2bfloat16((v0 - mu) * r * g[t]       + bta[t]);
    orow[t + 256] = __float2bfloat16((v1 - mu) * r * g[t + 256] + bta[t + 256]);
    orow[t + 512] = __float2bfloat16((v2 - mu) * r * g[t + 512] + bta[t + 512]);
}

// ---------------------------------------------------------------------------
// 4x4 supertile swizzle.
// ---------------------------------------------------------------------------
__device__ inline void swizzle44(int bid, int nx4, int& bx, int& by) {
    int g = bid >> 4, r = bid & 15;
    bx = (g % nx4) * 4 + (r & 3);
    by = (g / nx4) * 4 + (r >> 2);
}

__device__ inline float gelu_tanh(float x) {
    float x3 = x * x * x;
    float u = 0.7978845608028654f * (x + 0.044715f * x3);
    return 0.5f * x * (1.0f + tanhf(u));
}

// ---------------------------------------------------------------------------
// r18: TM=TN=128, BK=64 GEMM (qkv/fc) — m93 tile-size lever on top of the
// r17 swizzled gload_lds structure. 4 waves, each owns a 64x64 sub-tile
// (acc[4][4]); per K-step per wave: 32 MFMA vs 16 ds_read (2:1, double r17).
// LDS 32KB (BK=128 would halve occupancy — m132). Blocks drop 4x -> 4x A/B
// reuse, half the staging traffic.
// Swizzle (rule #21 both-sides, 64-elem rows): LDS chunk c of row r holds
// global chunk c^(r&7); read elem ^= (qm&7)*8; rows r/r+8 alias 2-way (free).
// ---------------------------------------------------------------------------
template <int ACT, int HAS_RES, int OUT_BF16>
__global__ __launch_bounds__(256) void gemm_t128_k64(const bf16* __restrict__ A,
                                                     const bf16* __restrict__ BT,
                                                     const float* __restrict__ bias,
                                                     const float* __restrict__ res,
                                                     void* __restrict__ Cout,
                                                     int N, int K, int nx) {
    __shared__ bf16 Asl[128][64];
    __shared__ bf16 Bsl[128][64];
    int bid = blockIdx.x;
    int bx = bid % nx, by = bid / nx;
    int tid = threadIdx.x;
    int m0 = by * 128, n0 = bx * 128;
    int wave = tid >> 6, lane = tid & 63;
    int qm = lane & 15, quad = lane >> 4;
    int wr = (wave & 1) * 64, wc = (wave >> 1) * 64;
    // staging: per wave 4 A + 4 B instrs; instr i covers rows wave*32+8i..+7.
    // lane L -> LDS row +L/8, chunk L&7; source chunk pre-swizzled ^ (L>>3).
    int srow = lane >> 3;                 // 0..7 == row&7 (base mult of 8)
    int scol = ((lane & 7) ^ srow) * 8;   // pre-swizzled source elem offset
    const bf16* ag = A  + (size_t)(m0 + wave * 32 + srow) * K + scol;
    const bf16* bg = BT + (size_t)(n0 + wave * 32 + srow) * K + scol;
    int xr = (qm & 7) << 3;               // read-side XOR (elements)

    v4f acc[4][4];
    #pragma unroll
    for (int i = 0; i < 4; i++)
        #pragma unroll
        for (int j = 0; j < 4; j++) acc[i][j] = {0.f, 0.f, 0.f, 0.f};

    for (int k0 = 0; k0 < K; k0 += 64) {
        __syncthreads();
        #pragma unroll
        for (int i = 0; i < 4; i++) {
            gload16(ag + (size_t)(8 * i) * K + k0, &Asl[wave * 32 + 8 * i][0]);
            gload16(bg + (size_t)(8 * i) * K + k0, &Bsl[wave * 32 + 8 * i][0]);
        }
        __syncthreads();
        #pragma unroll
        for (int kk = 0; kk < 64; kk += 32) {
            v8s a[4], b[4];
            #pragma unroll
            for (int m = 0; m < 4; m++)
                a[m] = *(const v8s*)&Asl[wr + m * 16 + qm][(kk + quad * 8) ^ xr];
            #pragma unroll
            for (int n = 0; n < 4; n++)
                b[n] = *(const v8s*)&Bsl[wc + n * 16 + qm][(kk + quad * 8) ^ xr];
            #pragma unroll
            for (int m = 0; m < 4; m++)
                #pragma unroll
                for (int n = 0; n < 4; n++)
                    acc[m][n] = __builtin_amdgcn_mfma_f32_16x16x32_bf16(a[m], b[n], acc[m][n], 0, 0, 0);
        }
    }

    #pragma unroll
    for (int n = 0; n < 4; n++) {
        int col = n0 + wc + n * 16 + qm;
        float bcol = bias[col];
        #pragma unroll
        for (int m = 0; m < 4; m++) {
            #pragma unroll
            for (int r = 0; r < 4; r++) {
                int row = m0 + wr + m * 16 + quad * 4 + r;
                float v = acc[m][n][r] + bcol;
                if (ACT == 1) v = gelu_tanh(v);
                if (HAS_RES) v += res[(size_t)row * N + col];
                if (OUT_BF16) ((bf16*)Cout)[(size_t)row * N + col] = __float2bfloat16(v);
                else          ((float*)Cout)[(size_t)row * N + col] = v;
            }
        }
    }
}

// ---------------------------------------------------------------------------
// TM=64 x TN=64, BK=128 GEMM (proj/out): r17-proven swizzled gload_lds.
// ---------------------------------------------------------------------------
template <int ACT, int HAS_RES, int OUT_BF16>
__global__ __launch_bounds__(256) void gemm_k128(const bf16* __restrict__ A,
                                                 const bf16* __restrict__ BT,
                                                 const float* __restrict__ bias,
                                                 const float* __restrict__ res,
                                                 void* __restrict__ Cout,
                                                 int N, int K, int nx4) {
    __shared__ bf16 Asl[64][128];
    __shared__ bf16 Bsl[64][128];
    int bx, by;
    swizzle44(blockIdx.x, nx4, bx, by);
    int tid = threadIdx.x;
    int m0 = by * 64, n0 = bx * 64;
    int wave = tid >> 6, lane = tid & 63;
    int qm = lane & 15, quad = lane >> 4;
    int srow = lane >> 4;
    int chnk = lane & 15;
    int sce = (chnk ^ srow) * 8;          // i even
    int sco = (chnk ^ (srow + 4)) * 8;    // i odd
    const bf16* ag = A  + (size_t)(m0 + wave * 16 + srow) * K;
    const bf16* bg = BT + (size_t)(n0 + wave * 16 + srow) * K;
    int xr = (qm & 7) << 3;               // read-side XOR (elements)

    v4f acc[4] = {{0.f,0.f,0.f,0.f},{0.f,0.f,0.f,0.f},{0.f,0.f,0.f,0.f},{0.f,0.f,0.f,0.f}};

    for (int k0 = 0; k0 < K; k0 += 128) {
        __syncthreads();
        #pragma unroll
        for (int i = 0; i < 4; i++) {
            int sc = (i & 1) ? sco : sce;
            gload16(ag + (size_t)(4 * i) * K + k0 + sc, &Asl[wave * 16 + 4 * i][0]);
            gload16(bg + (size_t)(4 * i) * K + k0 + sc, &Bsl[wave * 16 + 4 * i][0]);
        }
        __syncthreads();
        #pragma unroll
        for (int kc = 0; kc < 4; kc++) {
            v8s a = *(const v8s*)&Asl[wave * 16 + qm][(kc * 32 + quad * 8) ^ xr];
            #pragma unroll
            for (int n = 0; n < 4; n++) {
                v8s b = *(const v8s*)&Bsl[n * 16 + qm][(kc * 32 + quad * 8) ^ xr];
                acc[n] = __builtin_amdgcn_mfma_f32_16x16x32_bf16(a, b, acc[n], 0, 0, 0);
            }
        }
    }

    int col_l = lane & 15;
    #pragma unroll
    for (int t = 0; t < 4; t++) {
        int col = n0 + t * 16 + col_l;
        float bcol = bias[col];
        #pragma unroll
        for (int r = 0; r < 4; r++) {
            int row = m0 + wave * 16 + quad * 4 + r;
            float v = acc[t][r] + bcol;
            if (ACT == 1) v = gelu_tanh(v);
            if (HAS_RES) v += res[(size_t)row * N + col];
            if (OUT_BF16) ((bf16*)Cout)[(size_t)row * N + col] = __float2bfloat16(v);
            else          ((float*)Cout)[(size_t)row * N + col] = v;
        }
    }
}

// ---------------------------------------------------------------------------
// phi in place over proj columns of qkvp (bf16).
// ---------------------------------------------------------------------------
__global__ __launch_bounds__(256) void phi_exp_kernel(bf16* __restrict__ qkvp) {
    int s = blockIdx.x, z = blockIdx.z;
    int b = z >> 1, isK = z & 1;
    int t = threadIdx.x;
    int h = blockIdx.y * 4 + (t >> 6);
    int m = t & 63;
    size_t row = (size_t)b * SS + s;
    float qd = __bfloat162float(qkvp[row * NQ + isK * DD + h * DHH + m]);
    float sq = qd * qd;
    #pragma unroll
    for (int off = 32; off > 0; off >>= 1) sq += __shfl_xor(sq, off, 64);
    sq *= (1.0f / 16.0f);
    size_t pidx = row * NQ + PQOFF + isK * DD + h * DHH + m;
    float proj = __bfloat162float(qkvp[pidx]);
    qkvp[pidx] = __float2bfloat16(__expf(proj - sq) * 0.125f + EPS_PHI);
}

// ---------------------------------------------------------------------------
// Scan phase 1 (MFMA): per (b,h,c): StateT[d][m] = V^T @ phik ; Sk[m] = col-sum.
// ---------------------------------------------------------------------------
__global__ __launch_bounds__(256) void scan_sums_mfma(const bf16* __restrict__ qkvp,
                                                      float* __restrict__ StateT,
                                                      float* __restrict__ Sk) {
    int c = blockIdx.x, h = blockIdx.y, b = blockIdx.z;
    int bh = b * HH + h;
    int t = threadIdx.x;
    __shared__ bf16 vt[64][72];   // V^T[d][s]
    __shared__ bf16 kt[64][72];   // phik^T[m][s]
    int sr = t >> 4, cq = (t & 15) * 4;
    #pragma unroll
    for (int i = 0; i < 4; i++) {
        int s = sr + 16 * i;
        size_t rowg = ((size_t)b * SS + c * CC + s) * NQ + h * DHH;
        b4 vv = *(const b4*)&qkvp[rowg + VOFF  + cq];
        b4 kv = *(const b4*)&qkvp[rowg + PKOFF + cq];
        #pragma unroll
        for (int j = 0; j < 4; j++) {
            vt[cq + j][s] = vv.v[j];
            kt[cq + j][s] = kv.v[j];
        }
    }
    __syncthreads();
    int wave = t >> 6, lane = t & 63, qm = lane & 15, quad = lane >> 4;
    v4f acc[4] = {{0.f,0.f,0.f,0.f},{0.f,0.f,0.f,0.f},{0.f,0.f,0.f,0.f},{0.f,0.f,0.f,0.f}};
    #pragma unroll
    for (int k0 = 0; k0 < 64; k0 += 32) {
        v8s a = *(const v8s*)&vt[wave * 16 + qm][k0 + quad * 8];
        #pragma unroll
        for (int n = 0; n < 4; n++) {
            v8s bb = *(const v8s*)&kt[n * 16 + qm][k0 + quad * 8];
            acc[n] = __builtin_amdgcn_mfma_f32_16x16x32_bf16(a, bb, acc[n], 0, 0, 0);
        }
    }
    float* dst = StateT + ((size_t)bh * NC + c) * 4096;
    int col_l = lane & 15;
    #pragma unroll
    for (int n = 0; n < 4; n++)
        #pragma unroll
        for (int r = 0; r < 4; r++) {
            int d = wave * 16 + quad * 4 + r;
            dst[d * 64 + n * 16 + col_l] = acc[n][r];
        }
    if (t < 64) {
        float sum = 0.f;
        #pragma unroll 8
        for (int i = 0; i < 64; i++) sum += __bfloat162float(kt[t][i]);
        Sk[((size_t)bh * NC + c) * 64 + t] = sum;
    }
}

// ---------------------------------------------------------------------------
// Scan phase 2: in-place EXCLUSIVE prefix over chunks.
// ---------------------------------------------------------------------------
__global__ __launch_bounds__(256) void scan_prefix_kernel(float* __restrict__ Skv,
                                                          float* __restrict__ Sk) {
    int bh = blockIdx.y;
    int t = blockIdx.x * 256 + threadIdx.x;
    size_t base = (size_t)bh * NC * 4096 + t;
    float acc = 0.f;
    for (int c = 0; c < NC; c++) {
        float v = Skv[base + (size_t)c * 4096];
        Skv[base + (size_t)c * 4096] = acc;
        acc += v;
    }
    if (blockIdx.x == 0 && threadIdx.x < 64) {
        size_t b2 = (size_t)bh * NC * 64 + threadIdx.x;
        float a2 = 0.f;
        for (int c = 0; c < NC; c++) {
            float v = Sk[b2 + (size_t)c * 64];
            Sk[b2 + (size_t)c * 64] = a2;
            a2 += v;
        }
    }
}

// ---------------------------------------------------------------------------
// Scan phase 3 (MFMA): A1 = phiq@phik^T, mask tril -> P;
// acc = phiq@[StateT|SkPre]^T + P@[V|1]; tile4 col0 = den; attn = num/den.
// ---------------------------------------------------------------------------
__global__ __launch_bounds__(256) void scan_chunk_mfma(const bf16* __restrict__ qkvp,
                                                       const float* __restrict__ StateT,
                                                       const float* __restrict__ SkPre,
                                                       bf16* __restrict__ attn) {
    int c = blockIdx.x, h = blockIdx.y, b = blockIdx.z;
    int bh = b * HH + h;
    int t = threadIdx.x;
    __shared__ bf16 qs[64][72];
    __shared__ bf16 ks[64][72];
    __shared__ bf16 vt[80][72];
    __shared__ bf16 stl[80][72];
    __shared__ bf16 P[64][72];
    int sr = t >> 4, cq = (t & 15) * 4;
    const float* stg = StateT + ((size_t)bh * NC + c) * 4096;
    #pragma unroll
    for (int i = 0; i < 4; i++) {
        int s = sr + 16 * i;
        size_t rowg = ((size_t)b * SS + c * CC + s) * NQ + h * DHH;
        b4 qv = *(const b4*)&qkvp[rowg + PQOFF + cq];
        b4 kv = *(const b4*)&qkvp[rowg + PKOFF + cq];
        b4 vv = *(const b4*)&qkvp[rowg + VOFF  + cq];
        float4 sv = *(const float4*)&stg[s * 64 + cq];
        #pragma unroll
        for (int j = 0; j < 4; j++) {
            qs[s][cq + j] = qv.v[j];
            ks[s][cq + j] = kv.v[j];
            vt[cq + j][s] = vv.v[j];
        }
        stl[s][cq + 0] = __float2bfloat16(sv.x);
        stl[s][cq + 1] = __float2bfloat16(sv.y);
        stl[s][cq + 2] = __float2bfloat16(sv.z);
        stl[s][cq + 3] = __float2bfloat16(sv.w);
    }
    {
        int rr = 64 + (t >> 4);
        bf16 one = __float2bfloat16(rr == 64 ? 1.f : 0.f);
        vt[rr][cq + 0] = one; vt[rr][cq + 1] = one;
        vt[rr][cq + 2] = one; vt[rr][cq + 3] = one;
        if (rr == 64) {
            const float* skp = SkPre + ((size_t)bh * NC + c) * 64;
            float4 s4 = *(const float4*)&skp[cq];
            stl[64][cq + 0] = __float2bfloat16(s4.x);
            stl[64][cq + 1] = __float2bfloat16(s4.y);
            stl[64][cq + 2] = __float2bfloat16(s4.z);
            stl[64][cq + 3] = __float2bfloat16(s4.w);
        } else {
            bf16 z = __float2bfloat16(0.f);
            stl[rr][cq + 0] = z; stl[rr][cq + 1] = z;
            stl[rr][cq + 2] = z; stl[rr][cq + 3] = z;
        }
    }
    __syncthreads();
    int wave = t >> 6, lane = t & 63, qm = lane & 15, quad = lane >> 4;
    int col_l = lane & 15;
    int row0 = wave * 16;

    v4f a1[4] = {{0.f,0.f,0.f,0.f},{0.f,0.f,0.f,0.f},{0.f,0.f,0.f,0.f},{0.f,0.f,0.f,0.f}};
    #pragma unroll
    for (int k0 = 0; k0 < 64; k0 += 32) {
        v8s a = *(const v8s*)&qs[row0 + qm][k0 + quad * 8];
        #pragma unroll
        for (int n = 0; n < 4; n++) {
            v8s bb = *(const v8s*)&ks[n * 16 + qm][k0 + quad * 8];
            a1[n] = __builtin_amdgcn_mfma_f32_16x16x32_bf16(a, bb, a1[n], 0, 0, 0);
        }
    }
    #pragma unroll
    for (int n = 0; n < 4; n++)
        #pragma unroll
        for (int r = 0; r < 4; r++) {
            int row = row0 + quad * 4 + r;
            int col = n * 16 + col_l;
            float v = (col <= row) ? a1[n][r] : 0.f;
            P[row][col] = __float2bfloat16(v);
        }
    v4f acc[5] = {{0.f,0.f,0.f,0.f},{0.f,0.f,0.f,0.f},{0.f,0.f,0.f,0.f},
                  {0.f,0.f,0.f,0.f},{0.f,0.f,0.f,0.f}};
    #pragma unroll
    for (int k0 = 0; k0 < 64; k0 += 32) {
        v8s aq = *(const v8s*)&qs[row0 + qm][k0 + quad * 8];
        v8s ap = *(const v8s*)&P [row0 + qm][k0 + quad * 8];
        #pragma unroll
        for (int n = 0; n < 5; n++) {
            v8s b1 = *(const v8s*)&stl[n * 16 + qm][k0 + quad * 8];
            v8s b2 = *(const v8s*)&vt [n * 16 + qm][k0 + quad * 8];
            acc[n] = __builtin_amdgcn_mfma_f32_16x16x32_bf16(aq, b1, acc[n], 0, 0, 0);
            acc[n] = __builtin_amdgcn_mfma_f32_16x16x32_bf16(ap, b2, acc[n], 0, 0, 0);
        }
    }
    float den[4];
    #pragma unroll
    for (int r = 0; r < 4; r++)
        den[r] = __shfl(acc[4][r], (lane >> 4) << 4, 64);
    #pragma unroll
    for (int n = 0; n < 4; n++)
        #pragma unroll
        for (int r = 0; r < 4; r++) {
            int srow = row0 + quad * 4 + r;
            int d = n * 16 + col_l;
            attn[((size_t)b * SS + c * CC + srow) * DD + h * DHH + d] =
                __float2bfloat16(acc[n][r] / den[r]);
        }
}

// ---------------------------------------------------------------------------
extern "C" void kernel_launch(void* const* d_in, const int* in_sizes, int n_in,
                              void* d_out, int out_size, void* d_ws, size_t ws_size,
                              hipStream_t stream) {
    const float* x      = (const float*)d_in[0];
    const float* ln1_g  = (const float*)d_in[1];
    const float* ln1_b  = (const float*)d_in[2];
    const float* w_attn = (const float*)d_in[3];
    const float* b_attn = (const float*)d_in[4];
    const float* w_feat = (const float*)d_in[5];
    const float* w_proj = (const float*)d_in[6];
    const float* b_proj = (const float*)d_in[7];
    const float* ln2_g  = (const float*)d_in[8];
    const float* ln2_b  = (const float*)d_in[9];
    const float* w_fc   = (const float*)d_in[10];
    const float* b_fc   = (const float*)d_in[11];
    const float* w_out  = (const float*)d_in[12];
    const float* b_out  = (const float*)d_in[13];
    float* out = (float*)d_out;

    // f32 region
    float* ws = (float*)d_ws;
    size_t off = 0;
    float* buf_x1   = ws + off; off += (size_t)BS * DD;            // 1.57M f32
    float* buf_sk   = ws + off; off += (size_t)BB * HH * NC * MM;  // 24.6K
    float* bias_ext = ws + off; off += NQ;
    // bf16 region (16B-aligned: preceding counts are multiples of 4)
    bf16* wb = (bf16*)(ws + off);
    size_t boff = 0;
    bf16* buf_qkvp    = wb + boff; boff += (size_t)BS * NQ;        // 7.86M bf16
    bf16* buf_a_bf    = wb + boff; boff += (size_t)BS * DD;
    bf16* buf_attn_bf = wb + boff; boff += (size_t)BS * DD;
    bf16* wext_t      = wb + boff; boff += (size_t)NQ * DD;
    bf16* wproj_t     = wb + boff; boff += (size_t)DD * DD;
    bf16* wfc_t       = wb + boff; boff += (size_t)DFF * DD;
    bf16* wout_t      = wb + boff; boff += (size_t)DD * DFF;
    // Aliases: StateT (1.57M f32) over buf_x1 (x1 written after scan);
    //          fc bf16 (6.29M) over buf_qkvp head (qkvp dead after 4c).
    float* buf_skv   = buf_x1;
    bf16*  buf_fc_bf = buf_qkvp;

    // 0) weight prep (one transpose dispatch + fused FAVOR+ cols + bias copy)
    transpose_all_kernel<<<6912, 256, 0, stream>>>(w_attn, w_proj, w_fc, w_out,
                                                   wext_t, wproj_t, wfc_t, wout_t);
    fuse_feat_kernel<<<dim3(DD / 64, HH, 2), 256, 0, stream>>>(w_attn, b_attn, w_feat, wext_t, bias_ext);
    hipMemcpyAsync(bias_ext, b_attn, 3 * DD * sizeof(float), hipMemcpyDeviceToDevice, stream);

    // 1) a = LN1(x) -> bf16
    ln_kernel<<<BS, 256, 0, stream>>>(x, ln1_g, ln1_b, buf_a_bf);
    // 2) [qkv | proj_q | proj_k] = a @ W_ext + bias_ext -> bf16
    //    (128x128 tiles: 16 x 30 = 480 blocks, 12 K-steps)
    gemm_t128_k64<0, 0, 1><<<480, 256, 0, stream>>>(
        buf_a_bf, wext_t, bias_ext, nullptr, buf_qkvp, NQ, DD, 30);
    // 3) phi in place (bf16)
    phi_exp_kernel<<<dim3(SS, 3, 2 * BB), 256, 0, stream>>>(buf_qkvp);
    // 4a) per-chunk sums (MFMA)
    scan_sums_mfma<<<dim3(NC, HH, BB), 256, 0, stream>>>(buf_qkvp, buf_skv, buf_sk);
    // 4b) exclusive prefix over chunks
    scan_prefix_kernel<<<dim3(4096 / 256, BB * HH), 256, 0, stream>>>(buf_skv, buf_sk);
    // 4c) per-chunk masked-MFMA scan -> attn (bf16)
    scan_chunk_mfma<<<dim3(NC, HH, BB), 256, 0, stream>>>(
        buf_qkvp, buf_skv, buf_sk, buf_attn_bf);
    // 5) x1 = x + attn @ w_proj + b_proj  (64x64 tiles: 32 x 12 = 384 blocks)
    gemm_k128<0, 1, 0><<<384, 256, 0, stream>>>(
        buf_attn_bf, wproj_t, b_proj, x, buf_x1, DD, DD, 3);
    // 6) m = LN2(x1) -> bf16
    ln_kernel<<<BS, 256, 0, stream>>>(buf_x1, ln2_g, ln2_b, buf_a_bf);
    // 7) fc = gelu(m @ w_fc + b_fc) -> bf16  (128x128 tiles: 16 x 24 = 384 blocks)
    gemm_t128_k64<1, 0, 1><<<384, 256, 0, stream>>>(
        buf_a_bf, wfc_t, b_fc, nullptr, buf_fc_bf, DFF, DD, 24);
    // 8) out = x1 + fc @ w_out + b_out  (64x64 tiles: 32 x 12 = 384 blocks, 24 K-steps)
    gemm_k128<0, 1, 0><<<384, 256, 0, stream>>>(
        buf_fc_bf, wout_t, b_out, buf_x1, out, DD, DFF, 3);
}

// Round 4
// 235.826 us; speedup vs baseline: 1.0164x; 1.0164x over previous
//
#include <hip/hip_runtime.h>
#include <hip/hip_bf16.h>
#include <math.h>

// Problem constants
#define BB 2
#define SS 1024
#define DD 768
#define HH 12
#define DHH 64
#define MM 64
#define DFF 3072
#define BS (BB*SS)          // 2048 rows
#define EPS_LN 1e-5f
#define EPS_PHI 1e-6f
#define CC 64               // scan chunk length
#define NC (SS/CC)          // 16 chunks
#define NQ 3840             // q,k,v (2304) + proj_q (768) + proj_k (768)
#define PQOFF 2304
#define PKOFF 3072
#define VOFF  1536

typedef __hip_bfloat16 bf16;
using v8s = __attribute__((ext_vector_type(8))) short;   // 8 bf16 (MFMA A/B frag)
using v4f = __attribute__((ext_vector_type(4))) float;   // MFMA C/D frag
struct b4 { bf16 v[4]; };                                // 8B packed bf16 quad

// Direct global->LDS 16B async copy (width=16).
typedef const __attribute__((address_space(1))) void ga_void;
typedef __attribute__((address_space(3))) void ls_void;
__device__ __forceinline__ void gload16(const void* g, void* l) {
    __builtin_amdgcn_global_load_lds((ga_void*)g, (ls_void*)l, 16, 0, 0);
}

// ---------------------------------------------------------------------------
// r19: ALL weight prep in ONE dispatch: 4 transposes (bid<6912),
// fused FAVOR+ projection cols (6912..7199), bias copy (7200).
// ---------------------------------------------------------------------------
__global__ __launch_bounds__(256) void prep_kernel(const float* __restrict__ w_attn,
                                                   const float* __restrict__ w_proj,
                                                   const float* __restrict__ w_fc,
                                                   const float* __restrict__ w_out,
                                                   const float* __restrict__ b_attn,
                                                   const float* __restrict__ wfeat,
                                                   bf16* __restrict__ wext_t,
                                                   bf16* __restrict__ wproj_t,
                                                   bf16* __restrict__ wfc_t,
                                                   bf16* __restrict__ wout_t,
                                                   float* __restrict__ bias_ext) {
    __shared__ float smem[2 * 64 * 65];   // 33.3 KB; transpose path uses a slice
    int bid = blockIdx.x;
    int t = threadIdx.x;
    if (bid < 6912) {
        const float* in; bf16* outp; int K, N, xt, yt;
        if (bid < 1728)      { in = w_attn; outp = wext_t;  K = 768;  N = 2304; xt = bid % 72;          yt = bid / 72; }
        else if (bid < 2304) { int b = bid - 1728; in = w_proj; outp = wproj_t; K = 768;  N = 768;  xt = b % 24; yt = b / 24; }
        else if (bid < 4608) { int b = bid - 2304; in = w_fc;   outp = wfc_t;   K = 768;  N = 3072; xt = b % 96; yt = b / 96; }
        else                 { int b = bid - 4608; in = w_out;  outp = wout_t;  K = 3072; N = 768;  xt = b % 24; yt = b / 24; }
        float (*tt)[33] = (float(*)[33])smem;
        int tx = t & 31, ty = t >> 5;    // 32 x 8
        int n0 = xt * 32, k0 = yt * 32;
        #pragma unroll
        for (int i = ty; i < 32; i += 8)
            tt[i][tx] = in[(size_t)(k0 + i) * N + n0 + tx];
        __syncthreads();
        #pragma unroll
        for (int i = ty; i < 32; i += 8)
            outp[(size_t)(n0 + i) * K + k0 + tx] = __float2bfloat16(tt[tx][i]);
    } else if (bid < 7200) {
        int b2 = bid - 6912;
        int jb = b2 % 12, h = (b2 / 12) % 12, isK = b2 / 144;
        float (*wfT)[65] = (float(*)[65])smem;           // wfT[d][m] = scale*wf[m][d]
        float (*Wt)[65]  = (float(*)[65])(smem + 64 * 65); // Wt[j][d]
        int j0 = jb * 64;
        int base = isK * DD + h * DHH;
        const float scale = 0.35355339059327373f;  // 64^-0.25
        #pragma unroll
        for (int it = 0; it < 16; it++) {
            int idx = it * 256 + t;
            int m = idx >> 6, d = idx & 63;
            wfT[d][m] = scale * wfeat[m * DHH + d];
            Wt[idx >> 6][idx & 63] = w_attn[(size_t)(j0 + (idx >> 6)) * (3 * DD) + base + (idx & 63)];
        }
        __syncthreads();
        int jl = t & 63, mg = (t >> 6) * 16;
        for (int m = mg; m < mg + 16; m++) {
            float acc = 0.f;
            #pragma unroll 8
            for (int d = 0; d < 64; d++) acc += wfT[d][m] * Wt[jl][d];
            wext_t[(size_t)(PQOFF + isK * DD + h * DHH + m) * DD + j0 + jl] = __float2bfloat16(acc);
        }
        if (jb == 0 && t < 64) {
            float accb = 0.f;
            #pragma unroll 8
            for (int d = 0; d < 64; d++) accb += wfT[d][t] * b_attn[base + d];
            bias_ext[PQOFF + isK * DD + h * DHH + t] = accb;
        }
    } else {
        for (int i = t; i < 3 * DD; i += 256) bias_ext[i] = b_attn[i];
    }
}

// ---------------------------------------------------------------------------
// LayerNorm: one block per row, 256 threads; f32 in -> bf16 out.
// ---------------------------------------------------------------------------
__global__ __launch_bounds__(256) void ln_kernel(const float* __restrict__ x,
                                                 const float* __restrict__ g,
                                                 const float* __restrict__ bta,
                                                 bf16* __restrict__ out) {
    int row = blockIdx.x;
    int t = threadIdx.x;
    const float* xr = x + (size_t)row * DD;
    float v0 = xr[t], v1 = xr[t + 256], v2 = xr[t + 512];
    float s = v0 + v1 + v2;
    float s2 = v0 * v0 + v1 * v1 + v2 * v2;
    #pragma unroll
    for (int off = 32; off > 0; off >>= 1) {
        s  += __shfl_xor(s,  off, 64);
        s2 += __shfl_xor(s2, off, 64);
    }
    __shared__ float ls[4], ls2[4];
    if ((t & 63) == 0) { ls[t >> 6] = s; ls2[t >> 6] = s2; }
    __syncthreads();
    s  = ls[0] + ls[1] + ls[2] + ls[3];
    s2 = ls2[0] + ls2[1] + ls2[2] + ls2[3];
    float mu  = s * (1.0f / DD);
    float var = s2 * (1.0f / DD) - mu * mu;
    float r = rsqrtf(var + EPS_LN);
    bf16* orow = out + (size_t)row * DD;
    orow[t]       = __float2bfloat16((v0 - mu) * r * g[t]       + bta[t]);
    orow[t + 256] = __float2bfloat16((v1 - mu) * r * g[t + 256] + bta[t + 256]);
    orow[t + 512] = __float2bfloat16((v2 - mu) * r * g[t + 512] + bta[t + 512]);
}

// ---------------------------------------------------------------------------
// 4x4 supertile swizzle.
// ---------------------------------------------------------------------------
__device__ inline void swizzle44(int bid, int nx4, int& bx, int& by) {
    int g = bid >> 4, r = bid & 15;
    bx = (g % nx4) * 4 + (r & 3);
    by = (g / nx4) * 4 + (r >> 2);
}

__device__ inline float gelu_tanh(float x) {
    float x3 = x * x * x;
    float u = 0.7978845608028654f * (x + 0.044715f * x3);
    return 0.5f * x * (1.0f + tanhf(u));
}

// ---------------------------------------------------------------------------
// TM=64 x TN=64, BK=128 GEMM (qkv/fc) — r17-proven swizzled gload_lds.
// (r18's 128^2 tile REGRESSED: 480-block grid = <2 blocks/CU exposed the
// barrier drain; occupancy is the prerequisite for the 2-barrier loop.)
// ---------------------------------------------------------------------------
template <int ACT, int HAS_RES, int OUT_BF16>
__global__ __launch_bounds__(256) void gemm_k128(const bf16* __restrict__ A,
                                                 const bf16* __restrict__ BT,
                                                 const float* __restrict__ bias,
                                                 const float* __restrict__ res,
                                                 void* __restrict__ Cout,
                                                 int N, int K, int nx4) {
    __shared__ bf16 Asl[64][128];
    __shared__ bf16 Bsl[64][128];
    int bx, by;
    swizzle44(blockIdx.x, nx4, bx, by);
    int tid = threadIdx.x;
    int m0 = by * 64, n0 = bx * 64;
    int wave = tid >> 6, lane = tid & 63;
    int qm = lane & 15, quad = lane >> 4;
    int srow = lane >> 4;
    int chnk = lane & 15;
    int sce = (chnk ^ srow) * 8;          // i even
    int sco = (chnk ^ (srow + 4)) * 8;    // i odd
    const bf16* ag = A  + (size_t)(m0 + wave * 16 + srow) * K;
    const bf16* bg = BT + (size_t)(n0 + wave * 16 + srow) * K;
    int xr = (qm & 7) << 3;               // read-side XOR (elements)

    v4f acc[4] = {{0.f,0.f,0.f,0.f},{0.f,0.f,0.f,0.f},{0.f,0.f,0.f,0.f},{0.f,0.f,0.f,0.f}};

    for (int k0 = 0; k0 < K; k0 += 128) {
        __syncthreads();
        #pragma unroll
        for (int i = 0; i < 4; i++) {
            int sc = (i & 1) ? sco : sce;
            gload16(ag + (size_t)(4 * i) * K + k0 + sc, &Asl[wave * 16 + 4 * i][0]);
            gload16(bg + (size_t)(4 * i) * K + k0 + sc, &Bsl[wave * 16 + 4 * i][0]);
        }
        __syncthreads();
        #pragma unroll
        for (int kc = 0; kc < 4; kc++) {
            v8s a = *(const v8s*)&Asl[wave * 16 + qm][(kc * 32 + quad * 8) ^ xr];
            #pragma unroll
            for (int n = 0; n < 4; n++) {
                v8s b = *(const v8s*)&Bsl[n * 16 + qm][(kc * 32 + quad * 8) ^ xr];
                acc[n] = __builtin_amdgcn_mfma_f32_16x16x32_bf16(a, b, acc[n], 0, 0, 0);
            }
        }
    }

    int col_l = lane & 15;
    #pragma unroll
    for (int t = 0; t < 4; t++) {
        int col = n0 + t * 16 + col_l;
        float bcol = bias[col];
        #pragma unroll
        for (int r = 0; r < 4; r++) {
            int row = m0 + wave * 16 + quad * 4 + r;
            float v = acc[t][r] + bcol;
            if (ACT == 1) v = gelu_tanh(v);
            if (HAS_RES) v += res[(size_t)row * N + col];
            if (OUT_BF16) ((bf16*)Cout)[(size_t)row * N + col] = __float2bfloat16(v);
            else          ((float*)Cout)[(size_t)row * N + col] = v;
        }
    }
}

// ---------------------------------------------------------------------------
// TM=32 x TN=64, BK=128 GEMM (proj/out, N=768) — gload_lds + XOR swizzle.
// ---------------------------------------------------------------------------
template <int ACT, int HAS_RES, int OUT_BF16>
__global__ __launch_bounds__(256) void gemm_m32_k128(const bf16* __restrict__ A,
                                                     const bf16* __restrict__ BT,
                                                     const float* __restrict__ bias,
                                                     const float* __restrict__ res,
                                                     void* __restrict__ Cout,
                                                     int N, int K, int nx4) {
    __shared__ bf16 Asl[32][128];
    __shared__ bf16 Bsl[64][128];
    int bx, by;
    swizzle44(blockIdx.x, nx4, bx, by);
    int tid = threadIdx.x;
    int m0 = by * 32, n0 = bx * 64;
    int wave = tid >> 6, lane = tid & 63;
    int qm = lane & 15, quad = lane >> 4;
    int rowh = (wave & 1) * 16;
    int colh = (wave >> 1) * 32;
    int srow = lane >> 4;
    int chnk = lane & 15;
    int sce = (chnk ^ srow) * 8;          // i even
    int sco = (chnk ^ (srow + 4)) * 8;    // i odd
    const bf16* ag = A  + (size_t)(m0 + wave * 8  + srow) * K;
    const bf16* bg = BT + (size_t)(n0 + wave * 16 + srow) * K;
    int xr = (qm & 7) << 3;

    v4f acc[2] = {{0.f,0.f,0.f,0.f},{0.f,0.f,0.f,0.f}};

    for (int k0 = 0; k0 < K; k0 += 128) {
        __syncthreads();
        #pragma unroll
        for (int i = 0; i < 2; i++) {
            int sc = (i & 1) ? sco : sce;
            gload16(ag + (size_t)(4 * i) * K + k0 + sc, &Asl[wave * 8 + 4 * i][0]);
        }
        #pragma unroll
        for (int i = 0; i < 4; i++) {
            int sc = (i & 1) ? sco : sce;
            gload16(bg + (size_t)(4 * i) * K + k0 + sc, &Bsl[wave * 16 + 4 * i][0]);
        }
        __syncthreads();
        #pragma unroll
        for (int kc = 0; kc < 4; kc++) {
            v8s a  = *(const v8s*)&Asl[rowh + qm][(kc * 32 + quad * 8) ^ xr];
            v8s b0 = *(const v8s*)&Bsl[colh + qm][(kc * 32 + quad * 8) ^ xr];
            v8s b1 = *(const v8s*)&Bsl[colh + 16 + qm][(kc * 32 + quad * 8) ^ xr];
            acc[0] = __builtin_amdgcn_mfma_f32_16x16x32_bf16(a, b0, acc[0], 0, 0, 0);
            acc[1] = __builtin_amdgcn_mfma_f32_16x16x32_bf16(a, b1, acc[1], 0, 0, 0);
        }
    }

    #pragma unroll
    for (int ct = 0; ct < 2; ct++) {
        int col = n0 + colh + ct * 16 + qm;
        float bcol = bias[col];
        #pragma unroll
        for (int r = 0; r < 4; r++) {
            int row = m0 + rowh + quad * 4 + r;
            float v = acc[ct][r] + bcol;
            if (ACT == 1) v = gelu_tanh(v);
            if (HAS_RES) v += res[(size_t)row * N + col];
            if (OUT_BF16) ((bf16*)Cout)[(size_t)row * N + col] = __float2bfloat16(v);
            else          ((float*)Cout)[(size_t)row * N + col] = v;
        }
    }
}

// ---------------------------------------------------------------------------
// phi helper: per-row sq via 16-lane-group reduce; applied during staging.
// ---------------------------------------------------------------------------
__device__ __forceinline__ float rowsq16(b4 raw) {
    float sq = 0.f;
    #pragma unroll
    for (int j = 0; j < 4; j++) { float f = __bfloat162float(raw.v[j]); sq += f * f; }
    sq += __shfl_xor(sq, 1, 64); sq += __shfl_xor(sq, 2, 64);
    sq += __shfl_xor(sq, 4, 64); sq += __shfl_xor(sq, 8, 64);
    return sq * (1.0f / 16.0f);
}

// ---------------------------------------------------------------------------
// Scan phase 1 (MFMA), r19: phi(k) fused into staging (raw k + proj_k read;
// removes the separate phi_exp dispatch + its 12.6MB pass).
// StateT[d][m] = V^T @ phik ; Sk[m] = col-sum(phik).
// ---------------------------------------------------------------------------
__global__ __launch_bounds__(256) void scan_sums_mfma(const bf16* __restrict__ qkvp,
                                                      float* __restrict__ StateT,
                                                      float* __restrict__ Sk) {
    int c = blockIdx.x, h = blockIdx.y, b = blockIdx.z;
    int bh = b * HH + h;
    int t = threadIdx.x;
    __shared__ bf16 vt[64][72];   // V^T[d][s]
    __shared__ bf16 kt[64][72];   // phik^T[m][s]
    int sr = t >> 4, cq = (t & 15) * 4;
    #pragma unroll
    for (int i = 0; i < 4; i++) {
        int s = sr + 16 * i;
        size_t rowg = ((size_t)b * SS + c * CC + s) * NQ + h * DHH;
        b4 vv = *(const b4*)&qkvp[rowg + VOFF  + cq];
        b4 kr = *(const b4*)&qkvp[rowg + DD    + cq];   // raw k head
        b4 kp = *(const b4*)&qkvp[rowg + PKOFF + cq];   // proj_k
        float sq = rowsq16(kr);
        #pragma unroll
        for (int j = 0; j < 4; j++) {
            vt[cq + j][s] = vv.v[j];
            kt[cq + j][s] = __float2bfloat16(
                __expf(__bfloat162float(kp.v[j]) - sq) * 0.125f + EPS_PHI);
        }
    }
    __syncthreads();
    int wave = t >> 6, lane = t & 63, qm = lane & 15, quad = lane >> 4;
    v4f acc[4] = {{0.f,0.f,0.f,0.f},{0.f,0.f,0.f,0.f},{0.f,0.f,0.f,0.f},{0.f,0.f,0.f,0.f}};
    #pragma unroll
    for (int k0 = 0; k0 < 64; k0 += 32) {
        v8s a = *(const v8s*)&vt[wave * 16 + qm][k0 + quad * 8];
        #pragma unroll
        for (int n = 0; n < 4; n++) {
            v8s bb = *(const v8s*)&kt[n * 16 + qm][k0 + quad * 8];
            acc[n] = __builtin_amdgcn_mfma_f32_16x16x32_bf16(a, bb, acc[n], 0, 0, 0);
        }
    }
    float* dst = StateT + ((size_t)bh * NC + c) * 4096;
    int col_l = lane & 15;
    #pragma unroll
    for (int n = 0; n < 4; n++)
        #pragma unroll
        for (int r = 0; r < 4; r++) {
            int d = wave * 16 + quad * 4 + r;
            dst[d * 64 + n * 16 + col_l] = acc[n][r];
        }
    if (t < 64) {
        float sum = 0.f;
        #pragma unroll 8
        for (int i = 0; i < 64; i++) sum += __bfloat162float(kt[t][i]);
        Sk[((size_t)bh * NC + c) * 64 + t] = sum;
    }
}

// ---------------------------------------------------------------------------
// Scan phase 2: in-place EXCLUSIVE prefix over chunks.
// ---------------------------------------------------------------------------
__global__ __launch_bounds__(256) void scan_prefix_kernel(float* __restrict__ Skv,
                                                          float* __restrict__ Sk) {
    int bh = blockIdx.y;
    int t = blockIdx.x * 256 + threadIdx.x;
    size_t base = (size_t)bh * NC * 4096 + t;
    float acc = 0.f;
    for (int c = 0; c < NC; c++) {
        float v = Skv[base + (size_t)c * 4096];
        Skv[base + (size_t)c * 4096] = acc;
        acc += v;
    }
    if (blockIdx.x == 0 && threadIdx.x < 64) {
        size_t b2 = (size_t)bh * NC * 64 + threadIdx.x;
        float a2 = 0.f;
        for (int c = 0; c < NC; c++) {
            float v = Sk[b2 + (size_t)c * 64];
            Sk[b2 + (size_t)c * 64] = a2;
            a2 += v;
        }
    }
}

// ---------------------------------------------------------------------------
// Scan phase 3 (MFMA), r19: phi(q), phi(k) fused into staging.
// A1 = phiq@phik^T, mask tril -> P;
// acc = phiq@[StateT|SkPre]^T + P@[V|1]; tile4 col0 = den; attn = num/den.
// ---------------------------------------------------------------------------
__global__ __launch_bounds__(256) void scan_chunk_mfma(const bf16* __restrict__ qkvp,
                                                       const float* __restrict__ StateT,
                                                       const float* __restrict__ SkPre,
                                                       bf16* __restrict__ attn) {
    int c = blockIdx.x, h = blockIdx.y, b = blockIdx.z;
    int bh = b * HH + h;
    int t = threadIdx.x;
    __shared__ bf16 qs[64][72];
    __shared__ bf16 ks[64][72];
    __shared__ bf16 vt[80][72];
    __shared__ bf16 stl[80][72];
    __shared__ bf16 P[64][72];
    int sr = t >> 4, cq = (t & 15) * 4;
    const float* stg = StateT + ((size_t)bh * NC + c) * 4096;
    #pragma unroll
    for (int i = 0; i < 4; i++) {
        int s = sr + 16 * i;
        size_t rowg = ((size_t)b * SS + c * CC + s) * NQ + h * DHH;
        b4 qr = *(const b4*)&qkvp[rowg + 0     + cq];   // raw q head
        b4 qp = *(const b4*)&qkvp[rowg + PQOFF + cq];   // proj_q
        b4 kr = *(const b4*)&qkvp[rowg + DD    + cq];   // raw k head
        b4 kp = *(const b4*)&qkvp[rowg + PKOFF + cq];   // proj_k
        b4 vv = *(const b4*)&qkvp[rowg + VOFF  + cq];
        float4 sv = *(const float4*)&stg[s * 64 + cq];
        float sqq = rowsq16(qr);
        float sqk = rowsq16(kr);
        #pragma unroll
        for (int j = 0; j < 4; j++) {
            qs[s][cq + j] = __float2bfloat16(
                __expf(__bfloat162float(qp.v[j]) - sqq) * 0.125f + EPS_PHI);
            ks[s][cq + j] = __float2bfloat16(
                __expf(__bfloat162float(kp.v[j]) - sqk) * 0.125f + EPS_PHI);
            vt[cq + j][s] = vv.v[j];
        }
        stl[s][cq + 0] = __float2bfloat16(sv.x);
        stl[s][cq + 1] = __float2bfloat16(sv.y);
        stl[s][cq + 2] = __float2bfloat16(sv.z);
        stl[s][cq + 3] = __float2bfloat16(sv.w);
    }
    {
        int rr = 64 + (t >> 4);
        bf16 one = __float2bfloat16(rr == 64 ? 1.f : 0.f);
        vt[rr][cq + 0] = one; vt[rr][cq + 1] = one;
        vt[rr][cq + 2] = one; vt[rr][cq + 3] = one;
        if (rr == 64) {
            const float* skp = SkPre + ((size_t)bh * NC + c) * 64;
            float4 s4 = *(const float4*)&skp[cq];
            stl[64][cq + 0] = __float2bfloat16(s4.x);
            stl[64][cq + 1] = __float2bfloat16(s4.y);
            stl[64][cq + 2] = __float2bfloat16(s4.z);
            stl[64][cq + 3] = __float2bfloat16(s4.w);
        } else {
            bf16 z = __float2bfloat16(0.f);
            stl[rr][cq + 0] = z; stl[rr][cq + 1] = z;
            stl[rr][cq + 2] = z; stl[rr][cq + 3] = z;
        }
    }
    __syncthreads();
    int wave = t >> 6, lane = t & 63, qm = lane & 15, quad = lane >> 4;
    int col_l = lane & 15;
    int row0 = wave * 16;

    v4f a1[4] = {{0.f,0.f,0.f,0.f},{0.f,0.f,0.f,0.f},{0.f,0.f,0.f,0.f},{0.f,0.f,0.f,0.f}};
    #pragma unroll
    for (int k0 = 0; k0 < 64; k0 += 32) {
        v8s a = *(const v8s*)&qs[row0 + qm][k0 + quad * 8];
        #pragma unroll
        for (int n = 0; n < 4; n++) {
            v8s bb = *(const v8s*)&ks[n * 16 + qm][k0 + quad * 8];
            a1[n] = __builtin_amdgcn_mfma_f32_16x16x32_bf16(a, bb, a1[n], 0, 0, 0);
        }
    }
    #pragma unroll
    for (int n = 0; n < 4; n++)
        #pragma unroll
        for (int r = 0; r < 4; r++) {
            int row = row0 + quad * 4 + r;
            int col = n * 16 + col_l;
            float v = (col <= row) ? a1[n][r] : 0.f;
            P[row][col] = __float2bfloat16(v);
        }
    v4f acc[5] = {{0.f,0.f,0.f,0.f},{0.f,0.f,0.f,0.f},{0.f,0.f,0.f,0.f},
                  {0.f,0.f,0.f,0.f},{0.f,0.f,0.f,0.f}};
    #pragma unroll
    for (int k0 = 0; k0 < 64; k0 += 32) {
        v8s aq = *(const v8s*)&qs[row0 + qm][k0 + quad * 8];
        v8s ap = *(const v8s*)&P [row0 + qm][k0 + quad * 8];
        #pragma unroll
        for (int n = 0; n < 5; n++) {
            v8s b1 = *(const v8s*)&stl[n * 16 + qm][k0 + quad * 8];
            v8s b2 = *(const v8s*)&vt [n * 16 + qm][k0 + quad * 8];
            acc[n] = __builtin_amdgcn_mfma_f32_16x16x32_bf16(aq, b1, acc[n], 0, 0, 0);
            acc[n] = __builtin_amdgcn_mfma_f32_16x16x32_bf16(ap, b2, acc[n], 0, 0, 0);
        }
    }
    float den[4];
    #pragma unroll
    for (int r = 0; r < 4; r++)
        den[r] = __shfl(acc[4][r], (lane >> 4) << 4, 64);
    #pragma unroll
    for (int n = 0; n < 4; n++)
        #pragma unroll
        for (int r = 0; r < 4; r++) {
            int srow = row0 + quad * 4 + r;
            int d = n * 16 + col_l;
            attn[((size_t)b * SS + c * CC + srow) * DD + h * DHH + d] =
                __float2bfloat16(acc[n][r] / den[r]);
        }
}

// ---------------------------------------------------------------------------
extern "C" void kernel_launch(void* const* d_in, const int* in_sizes, int n_in,
                              void* d_out, int out_size, void* d_ws, size_t ws_size,
                              hipStream_t stream) {
    const float* x      = (const float*)d_in[0];
    const float* ln1_g  = (const float*)d_in[1];
    const float* ln1_b  = (const float*)d_in[2];
    const float* w_attn = (const float*)d_in[3];
    const float* b_attn = (const float*)d_in[4];
    const float* w_feat = (const float*)d_in[5];
    const float* w_proj = (const float*)d_in[6];
    const float* b_proj = (const float*)d_in[7];
    const float* ln2_g  = (const float*)d_in[8];
    const float* ln2_b  = (const float*)d_in[9];
    const float* w_fc   = (const float*)d_in[10];
    const float* b_fc   = (const float*)d_in[11];
    const float* w_out  = (const float*)d_in[12];
    const float* b_out  = (const float*)d_in[13];
    float* out = (float*)d_out;

    // f32 region
    float* ws = (float*)d_ws;
    size_t off = 0;
    float* buf_x1   = ws + off; off += (size_t)BS * DD;            // 1.57M f32
    float* buf_sk   = ws + off; off += (size_t)BB * HH * NC * MM;  // 24.6K
    float* bias_ext = ws + off; off += NQ;
    // bf16 region (16B-aligned: preceding counts are multiples of 4)
    bf16* wb = (bf16*)(ws + off);
    size_t boff = 0;
    bf16* buf_qkvp    = wb + boff; boff += (size_t)BS * NQ;        // 7.86M bf16
    bf16* buf_a_bf    = wb + boff; boff += (size_t)BS * DD;
    bf16* buf_attn_bf = wb + boff; boff += (size_t)BS * DD;
    bf16* wext_t      = wb + boff; boff += (size_t)NQ * DD;
    bf16* wproj_t     = wb + boff; boff += (size_t)DD * DD;
    bf16* wfc_t       = wb + boff; boff += (size_t)DFF * DD;
    bf16* wout_t      = wb + boff; boff += (size_t)DD * DFF;
    // Aliases: StateT (1.57M f32) over buf_x1 (x1 written after scan);
    //          fc bf16 (6.29M) over buf_qkvp head (qkvp dead after 4c).
    float* buf_skv   = buf_x1;
    bf16*  buf_fc_bf = buf_qkvp;

    // 0) all weight prep in one dispatch (transposes + FAVOR+ cols + bias)
    prep_kernel<<<7201, 256, 0, stream>>>(w_attn, w_proj, w_fc, w_out, b_attn, w_feat,
                                          wext_t, wproj_t, wfc_t, wout_t, bias_ext);
    // 1) a = LN1(x) -> bf16
    ln_kernel<<<BS, 256, 0, stream>>>(x, ln1_g, ln1_b, buf_a_bf);
    // 2) [qkv | proj_q | proj_k] = a @ W_ext + bias_ext -> bf16 (raw proj; phi fused downstream)
    gemm_k128<0, 0, 1><<<1920, 256, 0, stream>>>(
        buf_a_bf, wext_t, bias_ext, nullptr, buf_qkvp, NQ, DD, 15);
    // 3a) per-chunk sums (MFMA, phi-k fused)
    scan_sums_mfma<<<dim3(NC, HH, BB), 256, 0, stream>>>(buf_qkvp, buf_skv, buf_sk);
    // 3b) exclusive prefix over chunks
    scan_prefix_kernel<<<dim3(4096 / 256, BB * HH), 256, 0, stream>>>(buf_skv, buf_sk);
    // 3c) per-chunk masked-MFMA scan -> attn (bf16; phi-q/k fused)
    scan_chunk_mfma<<<dim3(NC, HH, BB), 256, 0, stream>>>(
        buf_qkvp, buf_skv, buf_sk, buf_attn_bf);
    // 4) x1 = x + attn @ w_proj + b_proj
    gemm_m32_k128<0, 1, 0><<<768, 256, 0, stream>>>(
        buf_attn_bf, wproj_t, b_proj, x, buf_x1, DD, DD, 3);
    // 5) m = LN2(x1) -> bf16
    ln_kernel<<<BS, 256, 0, stream>>>(buf_x1, ln2_g, ln2_b, buf_a_bf);
    // 6) fc = gelu(m @ w_fc + b_fc) -> bf16
    gemm_k128<1, 0, 1><<<1536, 256, 0, stream>>>(
        buf_a_bf, wfc_t, b_fc, nullptr, buf_fc_bf, DFF, DD, 12);
    // 7) out = x1 + fc @ w_out + b_out
    gemm_m32_k128<0, 1, 0><<<768, 256, 0, stream>>>(
        buf_fc_bf, wout_t, b_out, buf_x1, out, DD, DFF, 3);
}

// Round 6
// 227.909 us; speedup vs baseline: 1.0517x; 1.0347x over previous
//
#include <hip/hip_runtime.h>
#include <hip/hip_bf16.h>
#include <math.h>

// Problem constants
#define BB 2
#define SS 1024
#define DD 768
#define HH 12
#define DHH 64
#define MM 64
#define DFF 3072
#define BS (BB*SS)          // 2048 rows
#define EPS_LN 1e-5f
#define EPS_PHI 1e-6f
#define CC 64               // scan chunk length
#define NC (SS/CC)          // 16 chunks
#define NQ 3840             // q,k,v (2304) + proj_q (768) + proj_k (768)
#define PQOFF 2304
#define PKOFF 3072
#define VOFF  1536

typedef __hip_bfloat16 bf16;
using v8s = __attribute__((ext_vector_type(8))) short;   // 8 bf16 (MFMA A/B frag)
using v4f = __attribute__((ext_vector_type(4))) float;   // MFMA C/D frag
struct b4 { bf16 v[4]; };                                // 8B packed bf16 quad

// Direct global->LDS 16B async copy (width=16).
typedef const __attribute__((address_space(1))) void ga_void;
typedef __attribute__((address_space(3))) void ls_void;
__device__ __forceinline__ void gload16(const void* g, void* l) {
    __builtin_amdgcn_global_load_lds((ga_void*)g, (ls_void*)l, 16, 0, 0);
}

// ---------------------------------------------------------------------------
// r20 prep: BW-shaped transposes. r19 post-mortem: prep was 50us at 8% HBM
// (33MB of traffic = ~6us of ideal work) — 32x32 tiles with 64B writes.
// Now: 64x64 tiles, float4 reads (256B/row-quarter), [64][65] f32 LDS
// (stride 65 = conflict-free transpose), b4-packed 8B writes = 128B/row.
// bid<1728: transposes; 1728..2015: FAVOR+ cols; 2016: bias copy.
// ---------------------------------------------------------------------------
__global__ __launch_bounds__(256) void prep_kernel(const float* __restrict__ w_attn,
                                                   const float* __restrict__ w_proj,
                                                   const float* __restrict__ w_fc,
                                                   const float* __restrict__ w_out,
                                                   const float* __restrict__ b_attn,
                                                   const float* __restrict__ wfeat,
                                                   bf16* __restrict__ wext_t,
                                                   bf16* __restrict__ wproj_t,
                                                   bf16* __restrict__ wfc_t,
                                                   bf16* __restrict__ wout_t,
                                                   float* __restrict__ bias_ext) {
    __shared__ float smem[2 * 64 * 65];   // 33.3 KB (feat path needs both halves)
    int bid = blockIdx.x;
    int t = threadIdx.x;
    if (bid < 1728) {
        const float* in; bf16* outp; int K, N, xt, yt;
        if (bid < 432)       { in = w_attn; outp = wext_t;  K = 768;  N = 2304; xt = bid % 36; yt = bid / 36; }
        else if (bid < 576)  { int b = bid - 432;  in = w_proj; outp = wproj_t; K = 768;  N = 768;  xt = b % 12; yt = b / 12; }
        else if (bid < 1152) { int b = bid - 576;  in = w_fc;   outp = wfc_t;   K = 768;  N = 3072; xt = b % 48; yt = b / 48; }
        else                 { int b = bid - 1152; in = w_out;  outp = wout_t;  K = 3072; N = 768;  xt = b % 12; yt = b / 12; }
        float (*sm)[65] = (float(*)[65])smem;
        int n0 = xt * 64, k0 = yt * 64;
        int rr = t >> 4, cc = (t & 15) * 4;
        #pragma unroll
        for (int it = 0; it < 4; it++) {
            int kr = it * 16 + rr;
            float4 v = *(const float4*)&in[(size_t)(k0 + kr) * N + n0 + cc];
            sm[kr][cc + 0] = v.x; sm[kr][cc + 1] = v.y;
            sm[kr][cc + 2] = v.z; sm[kr][cc + 3] = v.w;
        }
        __syncthreads();
        #pragma unroll
        for (int it = 0; it < 4; it++) {
            int nr = it * 16 + rr;
            b4 o;
            #pragma unroll
            for (int j = 0; j < 4; j++) o.v[j] = __float2bfloat16(sm[cc + j][nr]);
            *(b4*)&outp[(size_t)(n0 + nr) * K + k0 + cc] = o;
        }
    } else if (bid < 2016) {
        int b2 = bid - 1728;
        int jb = b2 % 12, h = (b2 / 12) % 12, isK = b2 / 144;
        float (*wfT)[65] = (float(*)[65])smem;             // wfT[d][m] = scale*wf[m][d]
        float (*Wt)[65]  = (float(*)[65])(smem + 64 * 65); // Wt[j][d]
        int j0 = jb * 64;
        int base = isK * DD + h * DHH;
        const float scale = 0.35355339059327373f;  // 64^-0.25
        #pragma unroll
        for (int it = 0; it < 16; it++) {
            int idx = it * 256 + t;
            int m = idx >> 6, d = idx & 63;
            wfT[d][m] = scale * wfeat[m * DHH + d];
            Wt[idx >> 6][idx & 63] = w_attn[(size_t)(j0 + (idx >> 6)) * (3 * DD) + base + (idx & 63)];
        }
        __syncthreads();
        int jl = t & 63, mg = (t >> 6) * 16;
        for (int m = mg; m < mg + 16; m++) {
            float acc = 0.f;
            #pragma unroll 8
            for (int d = 0; d < 64; d++) acc += wfT[d][m] * Wt[jl][d];
            wext_t[(size_t)(PQOFF + isK * DD + h * DHH + m) * DD + j0 + jl] = __float2bfloat16(acc);
        }
        if (jb == 0 && t < 64) {
            float accb = 0.f;
            #pragma unroll 8
            for (int d = 0; d < 64; d++) accb += wfT[d][t] * b_attn[base + d];
            bias_ext[PQOFF + isK * DD + h * DHH + t] = accb;
        }
    } else {
        for (int i = t; i < 3 * DD; i += 256) bias_ext[i] = b_attn[i];
    }
}

// ---------------------------------------------------------------------------
// LayerNorm: one block per row, 256 threads; f32 in -> bf16 out.
// ---------------------------------------------------------------------------
__global__ __launch_bounds__(256) void ln_kernel(const float* __restrict__ x,
                                                 const float* __restrict__ g,
                                                 const float* __restrict__ bta,
                                                 bf16* __restrict__ out) {
    int row = blockIdx.x;
    int t = threadIdx.x;
    const float* xr = x + (size_t)row * DD;
    float v0 = xr[t], v1 = xr[t + 256], v2 = xr[t + 512];
    float s = v0 + v1 + v2;
    float s2 = v0 * v0 + v1 * v1 + v2 * v2;
    #pragma unroll
    for (int off = 32; off > 0; off >>= 1) {
        s  += __shfl_xor(s,  off, 64);
        s2 += __shfl_xor(s2, off, 64);
    }
    __shared__ float ls[4], ls2[4];
    if ((t & 63) == 0) { ls[t >> 6] = s; ls2[t >> 6] = s2; }
    __syncthreads();
    s  = ls[0] + ls[1] + ls[2] + ls[3];
    s2 = ls2[0] + ls2[1] + ls2[2] + ls2[3];
    float mu  = s * (1.0f / DD);
    float var = s2 * (1.0f / DD) - mu * mu;
    float r = rsqrtf(var + EPS_LN);
    bf16* orow = out + (size_t)row * DD;
    orow[t]       = __float2bfloat16((v0 - mu) * r * g[t]       + bta[t]);
    orow[t + 256] = __float2bfloat16((v1 - mu) * r * g[t + 256] + bta[t + 256]);
    orow[t + 512] = __float2bfloat16((v2 - mu) * r * g[t + 512] + bta[t + 512]);
}

// ---------------------------------------------------------------------------
// 4x4 supertile swizzle.
// ---------------------------------------------------------------------------
__device__ inline void swizzle44(int bid, int nx4, int& bx, int& by) {
    int g = bid >> 4, r = bid & 15;
    bx = (g % nx4) * 4 + (r & 3);
    by = (g / nx4) * 4 + (r >> 2);
}

__device__ inline float gelu_tanh(float x) {
    float x3 = x * x * x;
    float u = 0.7978845608028654f * (x + 0.044715f * x3);
    return 0.5f * x * (1.0f + tanhf(u));
}

// ---------------------------------------------------------------------------
// TM=64 x TN=64, BK=128 GEMM (qkv/fc) — r17-proven swizzled gload_lds.
// ---------------------------------------------------------------------------
template <int ACT, int HAS_RES, int OUT_BF16>
__global__ __launch_bounds__(256) void gemm_k128(const bf16* __restrict__ A,
                                                 const bf16* __restrict__ BT,
                                                 const float* __restrict__ bias,
                                                 const float* __restrict__ res,
                                                 void* __restrict__ Cout,
                                                 int N, int K, int nx4) {
    __shared__ bf16 Asl[64][128];
    __shared__ bf16 Bsl[64][128];
    int bx, by;
    swizzle44(blockIdx.x, nx4, bx, by);
    int tid = threadIdx.x;
    int m0 = by * 64, n0 = bx * 64;
    int wave = tid >> 6, lane = tid & 63;
    int qm = lane & 15, quad = lane >> 4;
    int srow = lane >> 4;
    int chnk = lane & 15;
    int sce = (chnk ^ srow) * 8;          // i even
    int sco = (chnk ^ (srow + 4)) * 8;    // i odd
    const bf16* ag = A  + (size_t)(m0 + wave * 16 + srow) * K;
    const bf16* bg = BT + (size_t)(n0 + wave * 16 + srow) * K;
    int xr = (qm & 7) << 3;               // read-side XOR (elements)

    v4f acc[4] = {{0.f,0.f,0.f,0.f},{0.f,0.f,0.f,0.f},{0.f,0.f,0.f,0.f},{0.f,0.f,0.f,0.f}};

    for (int k0 = 0; k0 < K; k0 += 128) {
        __syncthreads();
        #pragma unroll
        for (int i = 0; i < 4; i++) {
            int sc = (i & 1) ? sco : sce;
            gload16(ag + (size_t)(4 * i) * K + k0 + sc, &Asl[wave * 16 + 4 * i][0]);
            gload16(bg + (size_t)(4 * i) * K + k0 + sc, &Bsl[wave * 16 + 4 * i][0]);
        }
        __syncthreads();
        #pragma unroll
        for (int kc = 0; kc < 4; kc++) {
            v8s a = *(const v8s*)&Asl[wave * 16 + qm][(kc * 32 + quad * 8) ^ xr];
            #pragma unroll
            for (int n = 0; n < 4; n++) {
                v8s b = *(const v8s*)&Bsl[n * 16 + qm][(kc * 32 + quad * 8) ^ xr];
                acc[n] = __builtin_amdgcn_mfma_f32_16x16x32_bf16(a, b, acc[n], 0, 0, 0);
            }
        }
    }

    int col_l = lane & 15;
    #pragma unroll
    for (int t = 0; t < 4; t++) {
        int col = n0 + t * 16 + col_l;
        float bcol = bias[col];
        #pragma unroll
        for (int r = 0; r < 4; r++) {
            int row = m0 + wave * 16 + quad * 4 + r;
            float v = acc[t][r] + bcol;
            if (ACT == 1) v = gelu_tanh(v);
            if (HAS_RES) v += res[(size_t)row * N + col];
            if (OUT_BF16) ((bf16*)Cout)[(size_t)row * N + col] = __float2bfloat16(v);
            else          ((float*)Cout)[(size_t)row * N + col] = v;
        }
    }
}

// ---------------------------------------------------------------------------
// TM=32 x TN=64, BK=128 GEMM (proj/out, N=768) — gload_lds + XOR swizzle.
// ---------------------------------------------------------------------------
template <int ACT, int HAS_RES, int OUT_BF16>
__global__ __launch_bounds__(256) void gemm_m32_k128(const bf16* __restrict__ A,
                                                     const bf16* __restrict__ BT,
                                                     const float* __restrict__ bias,
                                                     const float* __restrict__ res,
                                                     void* __restrict__ Cout,
                                                     int N, int K, int nx4) {
    __shared__ bf16 Asl[32][128];
    __shared__ bf16 Bsl[64][128];
    int bx, by;
    swizzle44(blockIdx.x, nx4, bx, by);
    int tid = threadIdx.x;
    int m0 = by * 32, n0 = bx * 64;
    int wave = tid >> 6, lane = tid & 63;
    int qm = lane & 15, quad = lane >> 4;
    int rowh = (wave & 1) * 16;
    int colh = (wave >> 1) * 32;
    int srow = lane >> 4;
    int chnk = lane & 15;
    int sce = (chnk ^ srow) * 8;          // i even
    int sco = (chnk ^ (srow + 4)) * 8;    // i odd
    const bf16* ag = A  + (size_t)(m0 + wave * 8  + srow) * K;
    const bf16* bg = BT + (size_t)(n0 + wave * 16 + srow) * K;
    int xr = (qm & 7) << 3;

    v4f acc[2] = {{0.f,0.f,0.f,0.f},{0.f,0.f,0.f,0.f}};

    for (int k0 = 0; k0 < K; k0 += 128) {
        __syncthreads();
        #pragma unroll
        for (int i = 0; i < 2; i++) {
            int sc = (i & 1) ? sco : sce;
            gload16(ag + (size_t)(4 * i) * K + k0 + sc, &Asl[wave * 8 + 4 * i][0]);
        }
        #pragma unroll
        for (int i = 0; i < 4; i++) {
            int sc = (i & 1) ? sco : sce;
            gload16(bg + (size_t)(4 * i) * K + k0 + sc, &Bsl[wave * 16 + 4 * i][0]);
        }
        __syncthreads();
        #pragma unroll
        for (int kc = 0; kc < 4; kc++) {
            v8s a  = *(const v8s*)&Asl[rowh + qm][(kc * 32 + quad * 8) ^ xr];
            v8s b0 = *(const v8s*)&Bsl[colh + qm][(kc * 32 + quad * 8) ^ xr];
            v8s b1 = *(const v8s*)&Bsl[colh + 16 + qm][(kc * 32 + quad * 8) ^ xr];
            acc[0] = __builtin_amdgcn_mfma_f32_16x16x32_bf16(a, b0, acc[0], 0, 0, 0);
            acc[1] = __builtin_amdgcn_mfma_f32_16x16x32_bf16(a, b1, acc[1], 0, 0, 0);
        }
    }

    #pragma unroll
    for (int ct = 0; ct < 2; ct++) {
        int col = n0 + colh + ct * 16 + qm;
        float bcol = bias[col];
        #pragma unroll
        for (int r = 0; r < 4; r++) {
            int row = m0 + rowh + quad * 4 + r;
            float v = acc[ct][r] + bcol;
            if (ACT == 1) v = gelu_tanh(v);
            if (HAS_RES) v += res[(size_t)row * N + col];
            if (OUT_BF16) ((bf16*)Cout)[(size_t)row * N + col] = __float2bfloat16(v);
            else          ((float*)Cout)[(size_t)row * N + col] = v;
        }
    }
}

// ---------------------------------------------------------------------------
// phi helper: per-row sq via 16-lane-group reduce; applied during staging.
// ---------------------------------------------------------------------------
__device__ __forceinline__ float rowsq16(b4 raw) {
    float sq = 0.f;
    #pragma unroll
    for (int j = 0; j < 4; j++) { float f = __bfloat162float(raw.v[j]); sq += f * f; }
    sq += __shfl_xor(sq, 1, 64); sq += __shfl_xor(sq, 2, 64);
    sq += __shfl_xor(sq, 4, 64); sq += __shfl_xor(sq, 8, 64);
    return sq * (1.0f / 16.0f);
}

// ---------------------------------------------------------------------------
// Scan phase 1 (MFMA): phi(k) fused into staging.
// StateT[d][m] = V^T @ phik ; Sk[m] = col-sum(phik).
// ---------------------------------------------------------------------------
__global__ __launch_bounds__(256) void scan_sums_mfma(const bf16* __restrict__ qkvp,
                                                      float* __restrict__ StateT,
                                                      float* __restrict__ Sk) {
    int c = blockIdx.x, h = blockIdx.y, b = blockIdx.z;
    int bh = b * HH + h;
    int t = threadIdx.x;
    __shared__ bf16 vt[64][72];   // V^T[d][s]
    __shared__ bf16 kt[64][72];   // phik^T[m][s]
    int sr = t >> 4, cq = (t & 15) * 4;
    #pragma unroll
    for (int i = 0; i < 4; i++) {
        int s = sr + 16 * i;
        size_t rowg = ((size_t)b * SS + c * CC + s) * NQ + h * DHH;
        b4 vv = *(const b4*)&qkvp[rowg + VOFF  + cq];
        b4 kr = *(const b4*)&qkvp[rowg + DD    + cq];   // raw k head
        b4 kp = *(const b4*)&qkvp[rowg + PKOFF + cq];   // proj_k
        float sq = rowsq16(kr);
        #pragma unroll
        for (int j = 0; j < 4; j++) {
            vt[cq + j][s] = vv.v[j];
            kt[cq + j][s] = __float2bfloat16(
                __expf(__bfloat162float(kp.v[j]) - sq) * 0.125f + EPS_PHI);
        }
    }
    __syncthreads();
    int wave = t >> 6, lane = t & 63, qm = lane & 15, quad = lane >> 4;
    v4f acc[4] = {{0.f,0.f,0.f,0.f},{0.f,0.f,0.f,0.f},{0.f,0.f,0.f,0.f},{0.f,0.f,0.f,0.f}};
    #pragma unroll
    for (int k0 = 0; k0 < 64; k0 += 32) {
        v8s a = *(const v8s*)&vt[wave * 16 + qm][k0 + quad * 8];
        #pragma unroll
        for (int n = 0; n < 4; n++) {
            v8s bb = *(const v8s*)&kt[n * 16 + qm][k0 + quad * 8];
            acc[n] = __builtin_amdgcn_mfma_f32_16x16x32_bf16(a, bb, acc[n], 0, 0, 0);
        }
    }
    float* dst = StateT + ((size_t)bh * NC + c) * 4096;
    int col_l = lane & 15;
    #pragma unroll
    for (int n = 0; n < 4; n++)
        #pragma unroll
        for (int r = 0; r < 4; r++) {
            int d = wave * 16 + quad * 4 + r;
            dst[d * 64 + n * 16 + col_l] = acc[n][r];
        }
    if (t < 64) {
        float sum = 0.f;
        #pragma unroll 8
        for (int i = 0; i < 64; i++) sum += __bfloat162float(kt[t][i]);
        Sk[((size_t)bh * NC + c) * 64 + t] = sum;
    }
}

// ---------------------------------------------------------------------------
// Scan phase 2: in-place EXCLUSIVE prefix over chunks.
// ---------------------------------------------------------------------------
__global__ __launch_bounds__(256) void scan_prefix_kernel(float* __restrict__ Skv,
                                                          float* __restrict__ Sk) {
    int bh = blockIdx.y;
    int t = blockIdx.x * 256 + threadIdx.x;
    size_t base = (size_t)bh * NC * 4096 + t;
    float acc = 0.f;
    for (int c = 0; c < NC; c++) {
        float v = Skv[base + (size_t)c * 4096];
        Skv[base + (size_t)c * 4096] = acc;
        acc += v;
    }
    if (blockIdx.x == 0 && threadIdx.x < 64) {
        size_t b2 = (size_t)bh * NC * 64 + threadIdx.x;
        float a2 = 0.f;
        for (int c = 0; c < NC; c++) {
            float v = Sk[b2 + (size_t)c * 64];
            Sk[b2 + (size_t)c * 64] = a2;
            a2 += v;
        }
    }
}

// ---------------------------------------------------------------------------
// Scan phase 3 (MFMA): phi(q), phi(k) fused into staging.
// A1 = phiq@phik^T, mask tril -> P;
// acc = phiq@[StateT|SkPre]^T + P@[V|1]; tile4 col0 = den; attn = num/den.
// ---------------------------------------------------------------------------
__global__ __launch_bounds__(256) void scan_chunk_mfma(const bf16* __restrict__ qkvp,
                                                       const float* __restrict__ StateT,
                                                       const float* __restrict__ SkPre,
                                                       bf16* __restrict__ attn) {
    int c = blockIdx.x, h = blockIdx.y, b = blockIdx.z;
    int bh = b * HH + h;
    int t = threadIdx.x;
    __shared__ bf16 qs[64][72];
    __shared__ bf16 ks[64][72];
    __shared__ bf16 vt[80][72];
    __shared__ bf16 stl[80][72];
    __shared__ bf16 P[64][72];
    int sr = t >> 4, cq = (t & 15) * 4;
    const float* stg = StateT + ((size_t)bh * NC + c) * 4096;
    #pragma unroll
    for (int i = 0; i < 4; i++) {
        int s = sr + 16 * i;
        size_t rowg = ((size_t)b * SS + c * CC + s) * NQ + h * DHH;
        b4 qr = *(const b4*)&qkvp[rowg + 0     + cq];   // raw q head
        b4 qp = *(const b4*)&qkvp[rowg + PQOFF + cq];   // proj_q
        b4 kr = *(const b4*)&qkvp[rowg + DD    + cq];   // raw k head
        b4 kp = *(const b4*)&qkvp[rowg + PKOFF + cq];   // proj_k
        b4 vv = *(const b4*)&qkvp[rowg + VOFF  + cq];
        float4 sv = *(const float4*)&stg[s * 64 + cq];
        float sqq = rowsq16(qr);
        float sqk = rowsq16(kr);
        #pragma unroll
        for (int j = 0; j < 4; j++) {
            qs[s][cq + j] = __float2bfloat16(
                __expf(__bfloat162float(qp.v[j]) - sqq) * 0.125f + EPS_PHI);
            ks[s][cq + j] = __float2bfloat16(
                __expf(__bfloat162float(kp.v[j]) - sqk) * 0.125f + EPS_PHI);
            vt[cq + j][s] = vv.v[j];
        }
        stl[s][cq + 0] = __float2bfloat16(sv.x);
        stl[s][cq + 1] = __float2bfloat16(sv.y);
        stl[s][cq + 2] = __float2bfloat16(sv.z);
        stl[s][cq + 3] = __float2bfloat16(sv.w);
    }
    {
        int rr = 64 + (t >> 4);
        bf16 one = __float2bfloat16(rr == 64 ? 1.f : 0.f);
        vt[rr][cq + 0] = one; vt[rr][cq + 1] = one;
        vt[rr][cq + 2] = one; vt[rr][cq + 3] = one;
        if (rr == 64) {
            const float* skp = SkPre + ((size_t)bh * NC + c) * 64;
            float4 s4 = *(const float4*)&skp[cq];
            stl[64][cq + 0] = __float2bfloat16(s4.x);
            stl[64][cq + 1] = __float2bfloat16(s4.y);
            stl[64][cq + 2] = __float2bfloat16(s4.z);
            stl[64][cq + 3] = __float2bfloat16(s4.w);
        } else {
            bf16 z = __float2bfloat16(0.f);
            stl[rr][cq + 0] = z; stl[rr][cq + 1] = z;
            stl[rr][cq + 2] = z; stl[rr][cq + 3] = z;
        }
    }
    __syncthreads();
    int wave = t >> 6, lane = t & 63, qm = lane & 15, quad = lane >> 4;
    int col_l = lane & 15;
    int row0 = wave * 16;

    v4f a1[4] = {{0.f,0.f,0.f,0.f},{0.f,0.f,0.f,0.f},{0.f,0.f,0.f,0.f},{0.f,0.f,0.f,0.f}};
    #pragma unroll
    for (int k0 = 0; k0 < 64; k0 += 32) {
        v8s a = *(const v8s*)&qs[row0 + qm][k0 + quad * 8];
        #pragma unroll
        for (int n = 0; n < 4; n++) {
            v8s bb = *(const v8s*)&ks[n * 16 + qm][k0 + quad * 8];
            a1[n] = __builtin_amdgcn_mfma_f32_16x16x32_bf16(a, bb, a1[n], 0, 0, 0);
        }
    }
    #pragma unroll
    for (int n = 0; n < 4; n++)
        #pragma unroll
        for (int r = 0; r < 4; r++) {
            int row = row0 + quad * 4 + r;
            int col = n * 16 + col_l;
            float v = (col <= row) ? a1[n][r] : 0.f;
            P[row][col] = __float2bfloat16(v);
        }
    v4f acc[5] = {{0.f,0.f,0.f,0.f},{0.f,0.f,0.f,0.f},{0.f,0.f,0.f,0.f},
                  {0.f,0.f,0.f,0.f},{0.f,0.f,0.f,0.f}};
    #pragma unroll
    for (int k0 = 0; k0 < 64; k0 += 32) {
        v8s aq = *(const v8s*)&qs[row0 + qm][k0 + quad * 8];
        v8s ap = *(const v8s*)&P [row0 + qm][k0 + quad * 8];
        #pragma unroll
        for (int n = 0; n < 5; n++) {
            v8s b1 = *(const v8s*)&stl[n * 16 + qm][k0 + quad * 8];
            v8s b2 = *(const v8s*)&vt [n * 16 + qm][k0 + quad * 8];
            acc[n] = __builtin_amdgcn_mfma_f32_16x16x32_bf16(aq, b1, acc[n], 0, 0, 0);
            acc[n] = __builtin_amdgcn_mfma_f32_16x16x32_bf16(ap, b2, acc[n], 0, 0, 0);
        }
    }
    float den[4];
    #pragma unroll
    for (int r = 0; r < 4; r++)
        den[r] = __shfl(acc[4][r], (lane >> 4) << 4, 64);
    #pragma unroll
    for (int n = 0; n < 4; n++)
        #pragma unroll
        for (int r = 0; r < 4; r++) {
            int srow = row0 + quad * 4 + r;
            int d = n * 16 + col_l;
            attn[((size_t)b * SS + c * CC + srow) * DD + h * DHH + d] =
                __float2bfloat16(acc[n][r] / den[r]);
        }
}

// ---------------------------------------------------------------------------
extern "C" void kernel_launch(void* const* d_in, const int* in_sizes, int n_in,
                              void* d_out, int out_size, void* d_ws, size_t ws_size,
                              hipStream_t stream) {
    const float* x      = (const float*)d_in[0];
    const float* ln1_g  = (const float*)d_in[1];
    const float* ln1_b  = (const float*)d_in[2];
    const float* w_attn = (const float*)d_in[3];
    const float* b_attn = (const float*)d_in[4];
    const float* w_feat = (const float*)d_in[5];
    const float* w_proj = (const float*)d_in[6];
    const float* b_proj = (const float*)d_in[7];
    const float* ln2_g  = (const float*)d_in[8];
    const float* ln2_b  = (const float*)d_in[9];
    const float* w_fc   = (const float*)d_in[10];
    const float* b_fc   = (const float*)d_in[11];
    const float* w_out  = (const float*)d_in[12];
    const float* b_out  = (const float*)d_in[13];
    float* out = (float*)d_out;

    // f32 region
    float* ws = (float*)d_ws;
    size_t off = 0;
    float* buf_x1   = ws + off; off += (size_t)BS * DD;            // 1.57M f32
    float* buf_sk   = ws + off; off += (size_t)BB * HH * NC * MM;  // 24.6K
    float* bias_ext = ws + off; off += NQ;
    // bf16 region (16B-aligned: preceding counts are multiples of 4)
    bf16* wb = (bf16*)(ws + off);
    size_t boff = 0;
    bf16* buf_qkvp    = wb + boff; boff += (size_t)BS * NQ;        // 7.86M bf16
    bf16* buf_a_bf    = wb + boff; boff += (size_t)BS * DD;
    bf16* buf_attn_bf = wb + boff; boff += (size_t)BS * DD;
    bf16* wext_t      = wb + boff; boff += (size_t)NQ * DD;
    bf16* wproj_t     = wb + boff; boff += (size_t)DD * DD;
    bf16* wfc_t       = wb + boff; boff += (size_t)DFF * DD;
    bf16* wout_t      = wb + boff; boff += (size_t)DD * DFF;
    // Aliases: StateT (1.57M f32) over buf_x1 (x1 written after scan);
    //          fc bf16 (6.29M) over buf_qkvp head (qkvp dead after 4c).
    float* buf_skv   = buf_x1;
    bf16*  buf_fc_bf = buf_qkvp;

    // 0) all weight prep in one dispatch (transposes + FAVOR+ cols + bias)
    prep_kernel<<<2017, 256, 0, stream>>>(w_attn, w_proj, w_fc, w_out, b_attn, w_feat,
                                          wext_t, wproj_t, wfc_t, wout_t, bias_ext);
    // 1) a = LN1(x) -> bf16
    ln_kernel<<<BS, 256, 0, stream>>>(x, ln1_g, ln1_b, buf_a_bf);
    // 2) [qkv | proj_q | proj_k] = a @ W_ext + bias_ext -> bf16 (raw proj; phi fused downstream)
    gemm_k128<0, 0, 1><<<1920, 256, 0, stream>>>(
        buf_a_bf, wext_t, bias_ext, nullptr, buf_qkvp, NQ, DD, 15);
    // 3a) per-chunk sums (MFMA, phi-k fused)
    scan_sums_mfma<<<dim3(NC, HH, BB), 256, 0, stream>>>(buf_qkvp, buf_skv, buf_sk);
    // 3b) exclusive prefix over chunks
    scan_prefix_kernel<<<dim3(4096 / 256, BB * HH), 256, 0, stream>>>(buf_skv, buf_sk);
    // 3c) per-chunk masked-MFMA scan -> attn (bf16; phi-q/k fused)
    scan_chunk_mfma<<<dim3(NC, HH, BB), 256, 0, stream>>>(
        buf_qkvp, buf_skv, buf_sk, buf_attn_bf);
    // 4) x1 = x + attn @ w_proj + b_proj
    gemm_m32_k128<0, 1, 0><<<768, 256, 0, stream>>>(
        buf_attn_bf, wproj_t, b_proj, x, buf_x1, DD, DD, 3);
    // 5) m = LN2(x1) -> bf16
    ln_kernel<<<BS, 256, 0, stream>>>(buf_x1, ln2_g, ln2_b, buf_a_bf);
    // 6) fc = gelu(m @ w_fc + b_fc) -> bf16
    gemm_k128<1, 0, 1><<<1536, 256, 0, stream>>>(
        buf_a_bf, wfc_t, b_fc, nullptr, buf_fc_bf, DFF, DD, 12);
    // 7) out = x1 + fc @ w_out + b_out
    gemm_m32_k128<0, 1, 0><<<768, 256, 0, stream>>>(
        buf_fc_bf, wout_t, b_out, buf_x1, out, DD, DFF, 3);
}

// Round 7
// 227.856 us; speedup vs baseline: 1.0519x; 1.0002x over previous
//
#include <hip/hip_runtime.h>
#include <hip/hip_bf16.h>
#include <math.h>

// Problem constants
#define BB 2
#define SS 1024
#define DD 768
#define HH 12
#define DHH 64
#define MM 64
#define DFF 3072
#define BS (BB*SS)          // 2048 rows
#define EPS_LN 1e-5f
#define EPS_PHI 1e-6f
#define CC 64               // scan chunk length
#define NC (SS/CC)          // 16 chunks
#define NQ 3840             // q,k,v (2304) + proj_q (768) + proj_k (768)
#define PQOFF 2304
#define PKOFF 3072
#define VOFF  1536

typedef __hip_bfloat16 bf16;
using v8s = __attribute__((ext_vector_type(8))) short;   // 8 bf16 (MFMA A/B frag)
using v4f = __attribute__((ext_vector_type(4))) float;   // MFMA C/D frag
struct b4 { bf16 v[4]; };                                // 8B packed bf16 quad

// Direct global->LDS 16B async copy (width=16).
typedef const __attribute__((address_space(1))) void ga_void;
typedef __attribute__((address_space(3))) void ls_void;
__device__ __forceinline__ void gload16(const void* g, void* l) {
    __builtin_amdgcn_global_load_lds((ga_void*)g, (ls_void*)l, 16, 0, 0);
}

// ---------------------------------------------------------------------------
// r22 prep: LN1 (bid<2048) + BW-shaped transposes (2048..3775) +
// FAVOR+ fused cols (3776..4063) + bias copy (4064), one dispatch.
// ---------------------------------------------------------------------------
__global__ __launch_bounds__(256) void prep_kernel(const float* __restrict__ x,
                                                   const float* __restrict__ ln1_g,
                                                   const float* __restrict__ ln1_b,
                                                   const float* __restrict__ w_attn,
                                                   const float* __restrict__ w_proj,
                                                   const float* __restrict__ w_fc,
                                                   const float* __restrict__ w_out,
                                                   const float* __restrict__ b_attn,
                                                   const float* __restrict__ wfeat,
                                                   bf16* __restrict__ a_bf,
                                                   bf16* __restrict__ wext_t,
                                                   bf16* __restrict__ wproj_t,
                                                   bf16* __restrict__ wfc_t,
                                                   bf16* __restrict__ wout_t,
                                                   float* __restrict__ bias_ext) {
    __shared__ float smem[2 * 64 * 65];   // 33.3 KB (feat path needs both halves)
    int bid = blockIdx.x;
    int t = threadIdx.x;
    if (bid < 2048) {
        // --- LN1 path ---
        int row = bid;
        const float* xr = x + (size_t)row * DD;
        float v0 = xr[t], v1 = xr[t + 256], v2 = xr[t + 512];
        float s = v0 + v1 + v2;
        float s2 = v0 * v0 + v1 * v1 + v2 * v2;
        #pragma unroll
        for (int off = 32; off > 0; off >>= 1) {
            s  += __shfl_xor(s,  off, 64);
            s2 += __shfl_xor(s2, off, 64);
        }
        float* ls = smem; float* ls2 = smem + 4;
        if ((t & 63) == 0) { ls[t >> 6] = s; ls2[t >> 6] = s2; }
        __syncthreads();
        s  = ls[0] + ls[1] + ls[2] + ls[3];
        s2 = ls2[0] + ls2[1] + ls2[2] + ls2[3];
        float mu  = s * (1.0f / DD);
        float var = s2 * (1.0f / DD) - mu * mu;
        float r = rsqrtf(var + EPS_LN);
        bf16* orow = a_bf + (size_t)row * DD;
        orow[t]       = __float2bfloat16((v0 - mu) * r * ln1_g[t]       + ln1_b[t]);
        orow[t + 256] = __float2bfloat16((v1 - mu) * r * ln1_g[t + 256] + ln1_b[t + 256]);
        orow[t + 512] = __float2bfloat16((v2 - mu) * r * ln1_g[t + 512] + ln1_b[t + 512]);
    } else if (bid < 3776) {
        int b = bid - 2048;
        const float* in; bf16* outp; int K, N, xt, yt;
        if (b < 432)       { in = w_attn; outp = wext_t;  K = 768;  N = 2304; xt = b % 36; yt = b / 36; }
        else if (b < 576)  { int b1 = b - 432;  in = w_proj; outp = wproj_t; K = 768;  N = 768;  xt = b1 % 12; yt = b1 / 12; }
        else if (b < 1152) { int b1 = b - 576;  in = w_fc;   outp = wfc_t;   K = 768;  N = 3072; xt = b1 % 48; yt = b1 / 48; }
        else               { int b1 = b - 1152; in = w_out;  outp = wout_t;  K = 3072; N = 768;  xt = b1 % 12; yt = b1 / 12; }
        float (*sm)[65] = (float(*)[65])smem;
        int n0 = xt * 64, k0 = yt * 64;
        int rr = t >> 4, cc = (t & 15) * 4;
        #pragma unroll
        for (int it = 0; it < 4; it++) {
            int kr = it * 16 + rr;
            float4 v = *(const float4*)&in[(size_t)(k0 + kr) * N + n0 + cc];
            sm[kr][cc + 0] = v.x; sm[kr][cc + 1] = v.y;
            sm[kr][cc + 2] = v.z; sm[kr][cc + 3] = v.w;
        }
        __syncthreads();
        #pragma unroll
        for (int it = 0; it < 4; it++) {
            int nr = it * 16 + rr;
            b4 o;
            #pragma unroll
            for (int j = 0; j < 4; j++) o.v[j] = __float2bfloat16(sm[cc + j][nr]);
            *(b4*)&outp[(size_t)(n0 + nr) * K + k0 + cc] = o;
        }
    } else if (bid < 4064) {
        int b2 = bid - 3776;
        int jb = b2 % 12, h = (b2 / 12) % 12, isK = b2 / 144;
        float (*wfT)[65] = (float(*)[65])smem;             // wfT[d][m] = scale*wf[m][d]
        float (*Wt)[65]  = (float(*)[65])(smem + 64 * 65); // Wt[j][d]
        int j0 = jb * 64;
        int base = isK * DD + h * DHH;
        const float scale = 0.35355339059327373f;  // 64^-0.25
        #pragma unroll
        for (int it = 0; it < 16; it++) {
            int idx = it * 256 + t;
            int m = idx >> 6, d = idx & 63;
            wfT[d][m] = scale * wfeat[m * DHH + d];
            Wt[idx >> 6][idx & 63] = w_attn[(size_t)(j0 + (idx >> 6)) * (3 * DD) + base + (idx & 63)];
        }
        __syncthreads();
        int jl = t & 63, mg = (t >> 6) * 16;
        for (int m = mg; m < mg + 16; m++) {
            float acc = 0.f;
            #pragma unroll 8
            for (int d = 0; d < 64; d++) acc += wfT[d][m] * Wt[jl][d];
            wext_t[(size_t)(PQOFF + isK * DD + h * DHH + m) * DD + j0 + jl] = __float2bfloat16(acc);
        }
        if (jb == 0 && t < 64) {
            float accb = 0.f;
            #pragma unroll 8
            for (int d = 0; d < 64; d++) accb += wfT[d][t] * b_attn[base + d];
            bias_ext[PQOFF + isK * DD + h * DHH + t] = accb;
        }
    } else {
        for (int i = t; i < 3 * DD; i += 256) bias_ext[i] = b_attn[i];
    }
}

// ---------------------------------------------------------------------------
// LayerNorm (LN2): one block per row, 256 threads; f32 in -> bf16 out.
// ---------------------------------------------------------------------------
__global__ __launch_bounds__(256) void ln_kernel(const float* __restrict__ x,
                                                 const float* __restrict__ g,
                                                 const float* __restrict__ bta,
                                                 bf16* __restrict__ out) {
    int row = blockIdx.x;
    int t = threadIdx.x;
    const float* xr = x + (size_t)row * DD;
    float v0 = xr[t], v1 = xr[t + 256], v2 = xr[t + 512];
    float s = v0 + v1 + v2;
    float s2 = v0 * v0 + v1 * v1 + v2 * v2;
    #pragma unroll
    for (int off = 32; off > 0; off >>= 1) {
        s  += __shfl_xor(s,  off, 64);
        s2 += __shfl_xor(s2, off, 64);
    }
    __shared__ float ls[4], ls2[4];
    if ((t & 63) == 0) { ls[t >> 6] = s; ls2[t >> 6] = s2; }
    __syncthreads();
    s  = ls[0] + ls[1] + ls[2] + ls[3];
    s2 = ls2[0] + ls2[1] + ls2[2] + ls2[3];
    float mu  = s * (1.0f / DD);
    float var = s2 * (1.0f / DD) - mu * mu;
    float r = rsqrtf(var + EPS_LN);
    bf16* orow = out + (size_t)row * DD;
    orow[t]       = __float2bfloat16((v0 - mu) * r * g[t]       + bta[t]);
    orow[t + 256] = __float2bfloat16((v1 - mu) * r * g[t + 256] + bta[t + 256]);
    orow[t + 512] = __float2bfloat16((v2 - mu) * r * g[t + 512] + bta[t + 512]);
}

// ---------------------------------------------------------------------------
// 4x4 supertile swizzle.
// ---------------------------------------------------------------------------
__device__ inline void swizzle44(int bid, int nx4, int& bx, int& by) {
    int g = bid >> 4, r = bid & 15;
    bx = (g % nx4) * 4 + (r & 3);
    by = (g / nx4) * 4 + (r >> 2);
}

__device__ inline float gelu_tanh(float x) {
    float x3 = x * x * x;
    float u = 0.7978845608028654f * (x + 0.044715f * x3);
    return 0.5f * x * (1.0f + tanhf(u));
}

// ---------------------------------------------------------------------------
// TM=64 x TN=64, BK=128 GEMM — r17-proven swizzled gload_lds.
// r22 SQMODE (qkv only): blocks covering q/k head cols (n0<1536) do NOT
// store; they reduce ||head||^2/16 per row into sqbuf[row*24 + n0/64]
// (raw q/k never needed downstream — only phi(proj, sq) and V).
// ---------------------------------------------------------------------------
template <int ACT, int HAS_RES, int OUT_BF16, int SQMODE>
__global__ __launch_bounds__(256) void gemm_k128(const bf16* __restrict__ A,
                                                 const bf16* __restrict__ BT,
                                                 const float* __restrict__ bias,
                                                 const float* __restrict__ res,
                                                 void* __restrict__ Cout,
                                                 int N, int K, int nx4,
                                                 float* __restrict__ sqbuf) {
    __shared__ bf16 Asl[64][128];
    __shared__ bf16 Bsl[64][128];
    int bx, by;
    swizzle44(blockIdx.x, nx4, bx, by);
    int tid = threadIdx.x;
    int m0 = by * 64, n0 = bx * 64;
    int wave = tid >> 6, lane = tid & 63;
    int qm = lane & 15, quad = lane >> 4;
    int srow = lane >> 4;
    int chnk = lane & 15;
    int sce = (chnk ^ srow) * 8;          // i even
    int sco = (chnk ^ (srow + 4)) * 8;    // i odd
    const bf16* ag = A  + (size_t)(m0 + wave * 16 + srow) * K;
    const bf16* bg = BT + (size_t)(n0 + wave * 16 + srow) * K;
    int xr = (qm & 7) << 3;               // read-side XOR (elements)

    v4f acc[4] = {{0.f,0.f,0.f,0.f},{0.f,0.f,0.f,0.f},{0.f,0.f,0.f,0.f},{0.f,0.f,0.f,0.f}};

    for (int k0 = 0; k0 < K; k0 += 128) {
        __syncthreads();
        #pragma unroll
        for (int i = 0; i < 4; i++) {
            int sc = (i & 1) ? sco : sce;
            gload16(ag + (size_t)(4 * i) * K + k0 + sc, &Asl[wave * 16 + 4 * i][0]);
            gload16(bg + (size_t)(4 * i) * K + k0 + sc, &Bsl[wave * 16 + 4 * i][0]);
        }
        __syncthreads();
        #pragma unroll
        for (int kc = 0; kc < 4; kc++) {
            v8s a = *(const v8s*)&Asl[wave * 16 + qm][(kc * 32 + quad * 8) ^ xr];
            #pragma unroll
            for (int n = 0; n < 4; n++) {
                v8s b = *(const v8s*)&Bsl[n * 16 + qm][(kc * 32 + quad * 8) ^ xr];
                acc[n] = __builtin_amdgcn_mfma_f32_16x16x32_bf16(a, b, acc[n], 0, 0, 0);
            }
        }
    }

    int col_l = lane & 15;
    if (SQMODE && n0 < 1536) {
        int hidx = n0 >> 6;               // q heads 0..11, k heads 12..23
        #pragma unroll
        for (int r = 0; r < 4; r++) {
            float hsq = 0.f;
            #pragma unroll
            for (int t2 = 0; t2 < 4; t2++) {
                float v = acc[t2][r] + bias[n0 + t2 * 16 + col_l];
                hsq += v * v;
            }
            hsq += __shfl_xor(hsq, 1, 64); hsq += __shfl_xor(hsq, 2, 64);
            hsq += __shfl_xor(hsq, 4, 64); hsq += __shfl_xor(hsq, 8, 64);
            if (col_l == 0) {
                int row = m0 + wave * 16 + quad * 4 + r;
                sqbuf[row * 24 + hidx] = hsq * (1.0f / 16.0f);
            }
        }
        return;
    }
    #pragma unroll
    for (int t2 = 0; t2 < 4; t2++) {
        int col = n0 + t2 * 16 + col_l;
        float bcol = bias[col];
        #pragma unroll
        for (int r = 0; r < 4; r++) {
            int row = m0 + wave * 16 + quad * 4 + r;
            float v = acc[t2][r] + bcol;
            if (ACT == 1) v = gelu_tanh(v);
            if (HAS_RES) v += res[(size_t)row * N + col];
            if (OUT_BF16) ((bf16*)Cout)[(size_t)row * N + col] = __float2bfloat16(v);
            else          ((float*)Cout)[(size_t)row * N + col] = v;
        }
    }
}

// ---------------------------------------------------------------------------
// TM=32 x TN=64, BK=128 GEMM (proj/out, N=768) — gload_lds + XOR swizzle.
// ---------------------------------------------------------------------------
template <int ACT, int HAS_RES, int OUT_BF16>
__global__ __launch_bounds__(256) void gemm_m32_k128(const bf16* __restrict__ A,
                                                     const bf16* __restrict__ BT,
                                                     const float* __restrict__ bias,
                                                     const float* __restrict__ res,
                                                     void* __restrict__ Cout,
                                                     int N, int K, int nx4) {
    __shared__ bf16 Asl[32][128];
    __shared__ bf16 Bsl[64][128];
    int bx, by;
    swizzle44(blockIdx.x, nx4, bx, by);
    int tid = threadIdx.x;
    int m0 = by * 32, n0 = bx * 64;
    int wave = tid >> 6, lane = tid & 63;
    int qm = lane & 15, quad = lane >> 4;
    int rowh = (wave & 1) * 16;
    int colh = (wave >> 1) * 32;
    int srow = lane >> 4;
    int chnk = lane & 15;
    int sce = (chnk ^ srow) * 8;          // i even
    int sco = (chnk ^ (srow + 4)) * 8;    // i odd
    const bf16* ag = A  + (size_t)(m0 + wave * 8  + srow) * K;
    const bf16* bg = BT + (size_t)(n0 + wave * 16 + srow) * K;
    int xr = (qm & 7) << 3;

    v4f acc[2] = {{0.f,0.f,0.f,0.f},{0.f,0.f,0.f,0.f}};

    for (int k0 = 0; k0 < K; k0 += 128) {
        __syncthreads();
        #pragma unroll
        for (int i = 0; i < 2; i++) {
            int sc = (i & 1) ? sco : sce;
            gload16(ag + (size_t)(4 * i) * K + k0 + sc, &Asl[wave * 8 + 4 * i][0]);
        }
        #pragma unroll
        for (int i = 0; i < 4; i++) {
            int sc = (i & 1) ? sco : sce;
            gload16(bg + (size_t)(4 * i) * K + k0 + sc, &Bsl[wave * 16 + 4 * i][0]);
        }
        __syncthreads();
        #pragma unroll
        for (int kc = 0; kc < 4; kc++) {
            v8s a  = *(const v8s*)&Asl[rowh + qm][(kc * 32 + quad * 8) ^ xr];
            v8s b0 = *(const v8s*)&Bsl[colh + qm][(kc * 32 + quad * 8) ^ xr];
            v8s b1 = *(const v8s*)&Bsl[colh + 16 + qm][(kc * 32 + quad * 8) ^ xr];
            acc[0] = __builtin_amdgcn_mfma_f32_16x16x32_bf16(a, b0, acc[0], 0, 0, 0);
            acc[1] = __builtin_amdgcn_mfma_f32_16x16x32_bf16(a, b1, acc[1], 0, 0, 0);
        }
    }

    #pragma unroll
    for (int ct = 0; ct < 2; ct++) {
        int col = n0 + colh + ct * 16 + qm;
        float bcol = bias[col];
        #pragma unroll
        for (int r = 0; r < 4; r++) {
            int row = m0 + rowh + quad * 4 + r;
            float v = acc[ct][r] + bcol;
            if (ACT == 1) v = gelu_tanh(v);
            if (HAS_RES) v += res[(size_t)row * N + col];
            if (OUT_BF16) ((bf16*)Cout)[(size_t)row * N + col] = __float2bfloat16(v);
            else          ((float*)Cout)[(size_t)row * N + col] = v;
        }
    }
}

// ---------------------------------------------------------------------------
// Scan phase 1 (MFMA): phi(k) from proj_k + precomputed sq (r22).
// StateT[d][m] = V^T @ phik ; Sk[m] = col-sum(phik).
// ---------------------------------------------------------------------------
__global__ __launch_bounds__(256) void scan_sums_mfma(const bf16* __restrict__ qkvp,
                                                      const float* __restrict__ sqbuf,
                                                      float* __restrict__ StateT,
                                                      float* __restrict__ Sk) {
    int c = blockIdx.x, h = blockIdx.y, b = blockIdx.z;
    int bh = b * HH + h;
    int t = threadIdx.x;
    __shared__ bf16 vt[64][72];   // V^T[d][s]
    __shared__ bf16 kt[64][72];   // phik^T[m][s]
    int sr = t >> 4, cq = (t & 15) * 4;
    #pragma unroll
    for (int i = 0; i < 4; i++) {
        int s = sr + 16 * i;
        size_t grow = (size_t)b * SS + c * CC + s;
        size_t rowg = grow * NQ + h * DHH;
        b4 vv = *(const b4*)&qkvp[rowg + VOFF  + cq];
        b4 kp = *(const b4*)&qkvp[rowg + PKOFF + cq];   // proj_k
        float sq = sqbuf[grow * 24 + 12 + h];
        #pragma unroll
        for (int j = 0; j < 4; j++) {
            vt[cq + j][s] = vv.v[j];
            kt[cq + j][s] = __float2bfloat16(
                __expf(__bfloat162float(kp.v[j]) - sq) * 0.125f + EPS_PHI);
        }
    }
    __syncthreads();
    int wave = t >> 6, lane = t & 63, qm = lane & 15, quad = lane >> 4;
    v4f acc[4] = {{0.f,0.f,0.f,0.f},{0.f,0.f,0.f,0.f},{0.f,0.f,0.f,0.f},{0.f,0.f,0.f,0.f}};
    #pragma unroll
    for (int k0 = 0; k0 < 64; k0 += 32) {
        v8s a = *(const v8s*)&vt[wave * 16 + qm][k0 + quad * 8];
        #pragma unroll
        for (int n = 0; n < 4; n++) {
            v8s bb = *(const v8s*)&kt[n * 16 + qm][k0 + quad * 8];
            acc[n] = __builtin_amdgcn_mfma_f32_16x16x32_bf16(a, bb, acc[n], 0, 0, 0);
        }
    }
    float* dst = StateT + ((size_t)bh * NC + c) * 4096;
    int col_l = lane & 15;
    #pragma unroll
    for (int n = 0; n < 4; n++)
        #pragma unroll
        for (int r = 0; r < 4; r++) {
            int d = wave * 16 + quad * 4 + r;
            dst[d * 64 + n * 16 + col_l] = acc[n][r];
        }
    {   // parallel col-sum: 4 threads per m
        int m = t >> 2, j = t & 3;
        float sum = 0.f;
        #pragma unroll
        for (int i2 = 0; i2 < 16; i2++) sum += __bfloat162float(kt[m][j * 16 + i2]);
        sum += __shfl_xor(sum, 1, 64);
        sum += __shfl_xor(sum, 2, 64);
        if (j == 0) Sk[((size_t)bh * NC + c) * 64 + m] = sum;
    }
}

// ---------------------------------------------------------------------------
// Scan phase 2: in-place EXCLUSIVE prefix over chunks.
// ---------------------------------------------------------------------------
__global__ __launch_bounds__(256) void scan_prefix_kernel(float* __restrict__ Skv,
                                                          float* __restrict__ Sk) {
    int bh = blockIdx.y;
    int t = blockIdx.x * 256 + threadIdx.x;
    size_t base = (size_t)bh * NC * 4096 + t;
    float acc = 0.f;
    for (int c = 0; c < NC; c++) {
        float v = Skv[base + (size_t)c * 4096];
        Skv[base + (size_t)c * 4096] = acc;
        acc += v;
    }
    if (blockIdx.x == 0 && threadIdx.x < 64) {
        size_t b2 = (size_t)bh * NC * 64 + threadIdx.x;
        float a2 = 0.f;
        for (int c = 0; c < NC; c++) {
            float v = Sk[b2 + (size_t)c * 64];
            Sk[b2 + (size_t)c * 64] = a2;
            a2 += v;
        }
    }
}

// ---------------------------------------------------------------------------
// Scan phase 3 (MFMA), r22: phi from proj + precomputed sq; den via VALU
// (rowsum(P) + phiq.SkPre) — 5th MFMA tile and 80-row padding removed.
// acc = phiq@StateT^T + P@V; attn = acc/den.
// ---------------------------------------------------------------------------
__global__ __launch_bounds__(256) void scan_chunk_mfma(const bf16* __restrict__ qkvp,
                                                       const float* __restrict__ sqbuf,
                                                       const float* __restrict__ StateT,
                                                       const float* __restrict__ SkPre,
                                                       bf16* __restrict__ attn) {
    int c = blockIdx.x, h = blockIdx.y, b = blockIdx.z;
    int bh = b * HH + h;
    int t = threadIdx.x;
    __shared__ bf16 qs[64][72];
    __shared__ bf16 ks[64][72];
    __shared__ bf16 vt[64][72];
    __shared__ bf16 stl[64][72];
    __shared__ bf16 P[64][72];
    int sr = t >> 4, cq = (t & 15) * 4;
    const float* stg = StateT + ((size_t)bh * NC + c) * 4096;
    #pragma unroll
    for (int i = 0; i < 4; i++) {
        int s = sr + 16 * i;
        size_t grow = (size_t)b * SS + c * CC + s;
        size_t rowg = grow * NQ + h * DHH;
        b4 qp = *(const b4*)&qkvp[rowg + PQOFF + cq];   // proj_q
        b4 kp = *(const b4*)&qkvp[rowg + PKOFF + cq];   // proj_k
        b4 vv = *(const b4*)&qkvp[rowg + VOFF  + cq];
        float4 sv = *(const float4*)&stg[s * 64 + cq];
        float sqq = sqbuf[grow * 24 + h];
        float sqk = sqbuf[grow * 24 + 12 + h];
        #pragma unroll
        for (int j = 0; j < 4; j++) {
            qs[s][cq + j] = __float2bfloat16(
                __expf(__bfloat162float(qp.v[j]) - sqq) * 0.125f + EPS_PHI);
            ks[s][cq + j] = __float2bfloat16(
                __expf(__bfloat162float(kp.v[j]) - sqk) * 0.125f + EPS_PHI);
            vt[cq + j][s] = vv.v[j];
        }
        stl[s][cq + 0] = __float2bfloat16(sv.x);
        stl[s][cq + 1] = __float2bfloat16(sv.y);
        stl[s][cq + 2] = __float2bfloat16(sv.z);
        stl[s][cq + 3] = __float2bfloat16(sv.w);
    }
    __syncthreads();
    int wave = t >> 6, lane = t & 63, qm = lane & 15, quad = lane >> 4;
    int col_l = lane & 15;
    int row0 = wave * 16;

    v4f a1[4] = {{0.f,0.f,0.f,0.f},{0.f,0.f,0.f,0.f},{0.f,0.f,0.f,0.f},{0.f,0.f,0.f,0.f}};
    #pragma unroll
    for (int k0 = 0; k0 < 64; k0 += 32) {
        v8s a = *(const v8s*)&qs[row0 + qm][k0 + quad * 8];
        #pragma unroll
        for (int n = 0; n < 4; n++) {
            v8s bb = *(const v8s*)&ks[n * 16 + qm][k0 + quad * 8];
            a1[n] = __builtin_amdgcn_mfma_f32_16x16x32_bf16(a, bb, a1[n], 0, 0, 0);
        }
    }
    float denl[4] = {0.f, 0.f, 0.f, 0.f};
    #pragma unroll
    for (int n = 0; n < 4; n++)
        #pragma unroll
        for (int r = 0; r < 4; r++) {
            int row = row0 + quad * 4 + r;
            int col = n * 16 + col_l;
            float v = (col <= row) ? a1[n][r] : 0.f;
            P[row][col] = __float2bfloat16(v);
            denl[r] += v;
        }
    {   // + phiq . SkPre (cross-chunk part); lane handles m = qm*4..qm*4+3
        const float* skp = SkPre + ((size_t)bh * NC + c) * 64;
        float4 sk4 = *(const float4*)&skp[qm * 4];
        #pragma unroll
        for (int r = 0; r < 4; r++) {
            int row = row0 + quad * 4 + r;
            b4 qv = *(const b4*)&qs[row][qm * 4];
            denl[r] += __bfloat162float(qv.v[0]) * sk4.x
                     + __bfloat162float(qv.v[1]) * sk4.y
                     + __bfloat162float(qv.v[2]) * sk4.z
                     + __bfloat162float(qv.v[3]) * sk4.w;
        }
    }
    #pragma unroll
    for (int r = 0; r < 4; r++) {
        denl[r] += __shfl_xor(denl[r], 1, 64);
        denl[r] += __shfl_xor(denl[r], 2, 64);
        denl[r] += __shfl_xor(denl[r], 4, 64);
        denl[r] += __shfl_xor(denl[r], 8, 64);
    }
    v4f acc[4] = {{0.f,0.f,0.f,0.f},{0.f,0.f,0.f,0.f},{0.f,0.f,0.f,0.f},{0.f,0.f,0.f,0.f}};
    #pragma unroll
    for (int k0 = 0; k0 < 64; k0 += 32) {
        v8s aq = *(const v8s*)&qs[row0 + qm][k0 + quad * 8];
        v8s ap = *(const v8s*)&P [row0 + qm][k0 + quad * 8];
        #pragma unroll
        for (int n = 0; n < 4; n++) {
            v8s b1 = *(const v8s*)&stl[n * 16 + qm][k0 + quad * 8];
            v8s b2 = *(const v8s*)&vt [n * 16 + qm][k0 + quad * 8];
            acc[n] = __builtin_amdgcn_mfma_f32_16x16x32_bf16(aq, b1, acc[n], 0, 0, 0);
            acc[n] = __builtin_amdgcn_mfma_f32_16x16x32_bf16(ap, b2, acc[n], 0, 0, 0);
        }
    }
    #pragma unroll
    for (int n = 0; n < 4; n++)
        #pragma unroll
        for (int r = 0; r < 4; r++) {
            int srow = row0 + quad * 4 + r;
            int d = n * 16 + col_l;
            attn[((size_t)b * SS + c * CC + srow) * DD + h * DHH + d] =
                __float2bfloat16(acc[n][r] / denl[r]);
        }
}

// ---------------------------------------------------------------------------
extern "C" void kernel_launch(void* const* d_in, const int* in_sizes, int n_in,
                              void* d_out, int out_size, void* d_ws, size_t ws_size,
                              hipStream_t stream) {
    const float* x      = (const float*)d_in[0];
    const float* ln1_g  = (const float*)d_in[1];
    const float* ln1_b  = (const float*)d_in[2];
    const float* w_attn = (const float*)d_in[3];
    const float* b_attn = (const float*)d_in[4];
    const float* w_feat = (const float*)d_in[5];
    const float* w_proj = (const float*)d_in[6];
    const float* b_proj = (const float*)d_in[7];
    const float* ln2_g  = (const float*)d_in[8];
    const float* ln2_b  = (const float*)d_in[9];
    const float* w_fc   = (const float*)d_in[10];
    const float* b_fc   = (const float*)d_in[11];
    const float* w_out  = (const float*)d_in[12];
    const float* b_out  = (const float*)d_in[13];
    float* out = (float*)d_out;

    // f32 region
    float* ws = (float*)d_ws;
    size_t off = 0;
    float* buf_x1   = ws + off; off += (size_t)BS * DD;            // 1.57M f32
    float* buf_sk   = ws + off; off += (size_t)BB * HH * NC * MM;  // 24.6K
    float* bias_ext = ws + off; off += NQ;
    float* buf_sq   = ws + off; off += (size_t)BS * 24;            // ||head||^2/16
    // bf16 region (16B-aligned: preceding counts are multiples of 4)
    bf16* wb = (bf16*)(ws + off);
    size_t boff = 0;
    bf16* buf_qkvp    = wb + boff; boff += (size_t)BS * NQ;        // 7.86M bf16
    bf16* buf_a_bf    = wb + boff; boff += (size_t)BS * DD;
    bf16* buf_attn_bf = wb + boff; boff += (size_t)BS * DD;
    bf16* wext_t      = wb + boff; boff += (size_t)NQ * DD;
    bf16* wproj_t     = wb + boff; boff += (size_t)DD * DD;
    bf16* wfc_t       = wb + boff; boff += (size_t)DFF * DD;
    bf16* wout_t      = wb + boff; boff += (size_t)DD * DFF;
    // Aliases: StateT (1.57M f32) over buf_x1 (x1 written after scan);
    //          fc bf16 (6.29M) over buf_qkvp head (qkvp dead after scan).
    float* buf_skv   = buf_x1;
    bf16*  buf_fc_bf = buf_qkvp;

    // 0) LN1 + all weight prep in one dispatch
    prep_kernel<<<4065, 256, 0, stream>>>(x, ln1_g, ln1_b,
                                          w_attn, w_proj, w_fc, w_out, b_attn, w_feat,
                                          buf_a_bf, wext_t, wproj_t, wfc_t, wout_t, bias_ext);
    // 1) [qkv | proj] = a @ W_ext + bias_ext; q/k head tiles -> sq only
    gemm_k128<0, 0, 1, 1><<<1920, 256, 0, stream>>>(
        buf_a_bf, wext_t, bias_ext, nullptr, buf_qkvp, NQ, DD, 15, buf_sq);
    // 2a) per-chunk sums (MFMA, phi-k from sq)
    scan_sums_mfma<<<dim3(NC, HH, BB), 256, 0, stream>>>(buf_qkvp, buf_sq, buf_skv, buf_sk);
    // 2b) exclusive prefix over chunks
    scan_prefix_kernel<<<dim3(4096 / 256, BB * HH), 256, 0, stream>>>(buf_skv, buf_sk);
    // 2c) per-chunk masked-MFMA scan -> attn
    scan_chunk_mfma<<<dim3(NC, HH, BB), 256, 0, stream>>>(
        buf_qkvp, buf_sq, buf_skv, buf_sk, buf_attn_bf);
    // 3) x1 = x + attn @ w_proj + b_proj
    gemm_m32_k128<0, 1, 0><<<768, 256, 0, stream>>>(
        buf_attn_bf, wproj_t, b_proj, x, buf_x1, DD, DD, 3);
    // 4) m = LN2(x1) -> bf16
    ln_kernel<<<BS, 256, 0, stream>>>(buf_x1, ln2_g, ln2_b, buf_a_bf);
    // 5) fc = gelu(m @ w_fc + b_fc) -> bf16
    gemm_k128<1, 0, 1, 0><<<1536, 256, 0, stream>>>(
        buf_a_bf, wfc_t, b_fc, nullptr, buf_fc_bf, DFF, DD, 12, nullptr);
    // 6) out = x1 + fc @ w_out + b_out
    gemm_m32_k128<0, 1, 0><<<768, 256, 0, stream>>>(
        buf_fc_bf, wout_t, b_out, buf_x1, out, DD, DFF, 3);
}

// Round 8
// 211.395 us; speedup vs baseline: 1.1339x; 1.0779x over previous
//
#include <hip/hip_runtime.h>
#include <hip/hip_bf16.h>
#include <math.h>

// Problem constants
#define BB 2
#define SS 1024
#define DD 768
#define HH 12
#define DHH 64
#define MM 64
#define DFF 3072
#define BS (BB*SS)          // 2048 rows
#define EPS_LN 1e-5f
#define EPS_PHI 1e-6f
#define CC 64               // scan chunk length
#define NC (SS/CC)          // 16 chunks
#define NQ 3840             // q,k,v (2304) + proj_q (768) + proj_k (768)
#define PQOFF 2304
#define PKOFF 3072
#define VOFF  1536

typedef __hip_bfloat16 bf16;
using v8s = __attribute__((ext_vector_type(8))) short;   // 8 bf16 (MFMA A/B frag)
using v4f = __attribute__((ext_vector_type(4))) float;   // MFMA C/D frag
struct b4 { bf16 v[4]; };                                // 8B packed bf16 quad

// Direct global->LDS 16B async copy (width=16).
typedef const __attribute__((address_space(1))) void ga_void;
typedef __attribute__((address_space(3))) void ls_void;
__device__ __forceinline__ void gload16(const void* g, void* l) {
    __builtin_amdgcn_global_load_lds((ga_void*)g, (ls_void*)l, 16, 0, 0);
}

// ---------------------------------------------------------------------------
// r23 feat kernel (split from prep): FAVOR+ fused cols + bias.
// r22 post-mortem: merged prep sat at ~1 block/CU (33.3KB LDS cap applied to
// ALL 4065 blocks) and feat's scalar 64-chain dot was a ~5us/block serial
// tail. Now: natural-layout staging (no LDS transpose at all) + float4 dot
// with 16 independent v4f accumulators (ILP), own dispatch.
// bid<288: feat; bid==288: bias copy.
// ---------------------------------------------------------------------------
__global__ __launch_bounds__(256) void feat_kernel(const float* __restrict__ w_attn,
                                                   const float* __restrict__ b_attn,
                                                   const float* __restrict__ wfeat,
                                                   bf16* __restrict__ wext_t,
                                                   float* __restrict__ bias_ext) {
    __shared__ float wfTm[64][68];  // wfTm[m][d] = scale*wf[m][d]
    __shared__ float Wt[64][68];    // Wt[j][d]   = w_attn[j0+j][base+d]
    int bid = blockIdx.x;
    int t = threadIdx.x;
    if (bid == 288) {
        for (int i = t; i < 3 * DD; i += 256) bias_ext[i] = b_attn[i];
        return;
    }
    int jb = bid % 12, h = (bid / 12) % 12, isK = bid / 144;
    int j0 = jb * 64;
    int base = isK * DD + h * DHH;
    const float scale = 0.35355339059327373f;  // 64^-0.25
    #pragma unroll
    for (int it = 0; it < 4; it++) {
        int fidx = it * 256 + t;                 // 1024 float4s
        int r = fidx >> 4, dc = (fidx & 15) * 4;
        float4 wv = *(const float4*)&wfeat[r * DHH + dc];
        wfTm[r][dc + 0] = scale * wv.x; wfTm[r][dc + 1] = scale * wv.y;
        wfTm[r][dc + 2] = scale * wv.z; wfTm[r][dc + 3] = scale * wv.w;
        float4 av = *(const float4*)&w_attn[(size_t)(j0 + r) * (3 * DD) + base + dc];
        Wt[r][dc + 0] = av.x; Wt[r][dc + 1] = av.y;
        Wt[r][dc + 2] = av.z; Wt[r][dc + 3] = av.w;
    }
    __syncthreads();
    int jl = t & 63, mg = (t >> 6) * 16;
    v4f acc[16];
    #pragma unroll
    for (int mi = 0; mi < 16; mi++) acc[mi] = {0.f, 0.f, 0.f, 0.f};
    #pragma unroll
    for (int dc = 0; dc < 16; dc++) {
        v4f wv = *(const v4f*)&Wt[jl][dc * 4];
        #pragma unroll
        for (int mi = 0; mi < 16; mi++) {
            v4f fv = *(const v4f*)&wfTm[mg + mi][dc * 4];
            acc[mi] += fv * wv;
        }
    }
    #pragma unroll
    for (int mi = 0; mi < 16; mi++) {
        float s = acc[mi][0] + acc[mi][1] + acc[mi][2] + acc[mi][3];
        wext_t[(size_t)(PQOFF + isK * DD + h * DHH + mg + mi) * DD + j0 + jl] = __float2bfloat16(s);
    }
    if (jb == 0 && t < 64) {
        float accb = 0.f;
        #pragma unroll 8
        for (int d = 0; d < 64; d++) accb += wfTm[t][d] * b_attn[base + d];
        bias_ext[PQOFF + isK * DD + h * DHH + t] = accb;
    }
}

// ---------------------------------------------------------------------------
// r23 prep_main: LN1 (bid<2048) + BW-shaped transposes (2048..3775).
// LDS now 16.9KB -> 8 blocks/CU (feat's 33.3KB no longer caps residency).
// ---------------------------------------------------------------------------
__global__ __launch_bounds__(256) void prep_main(const float* __restrict__ x,
                                                 const float* __restrict__ ln1_g,
                                                 const float* __restrict__ ln1_b,
                                                 const float* __restrict__ w_attn,
                                                 const float* __restrict__ w_proj,
                                                 const float* __restrict__ w_fc,
                                                 const float* __restrict__ w_out,
                                                 bf16* __restrict__ a_bf,
                                                 bf16* __restrict__ wext_t,
                                                 bf16* __restrict__ wproj_t,
                                                 bf16* __restrict__ wfc_t,
                                                 bf16* __restrict__ wout_t) {
    __shared__ float smem[64 * 65];   // 16.6 KB
    int bid = blockIdx.x;
    int t = threadIdx.x;
    if (bid < 2048) {
        // --- LN1 path ---
        int row = bid;
        const float* xr = x + (size_t)row * DD;
        float v0 = xr[t], v1 = xr[t + 256], v2 = xr[t + 512];
        float s = v0 + v1 + v2;
        float s2 = v0 * v0 + v1 * v1 + v2 * v2;
        #pragma unroll
        for (int off = 32; off > 0; off >>= 1) {
            s  += __shfl_xor(s,  off, 64);
            s2 += __shfl_xor(s2, off, 64);
        }
        float* ls = smem; float* ls2 = smem + 4;
        if ((t & 63) == 0) { ls[t >> 6] = s; ls2[t >> 6] = s2; }
        __syncthreads();
        s  = ls[0] + ls[1] + ls[2] + ls[3];
        s2 = ls2[0] + ls2[1] + ls2[2] + ls2[3];
        float mu  = s * (1.0f / DD);
        float var = s2 * (1.0f / DD) - mu * mu;
        float r = rsqrtf(var + EPS_LN);
        bf16* orow = a_bf + (size_t)row * DD;
        orow[t]       = __float2bfloat16((v0 - mu) * r * ln1_g[t]       + ln1_b[t]);
        orow[t + 256] = __float2bfloat16((v1 - mu) * r * ln1_g[t + 256] + ln1_b[t + 256]);
        orow[t + 512] = __float2bfloat16((v2 - mu) * r * ln1_g[t + 512] + ln1_b[t + 512]);
    } else {
        int b = bid - 2048;
        const float* in; bf16* outp; int K, N, xt, yt;
        if (b < 432)       { in = w_attn; outp = wext_t;  K = 768;  N = 2304; xt = b % 36; yt = b / 36; }
        else if (b < 576)  { int b1 = b - 432;  in = w_proj; outp = wproj_t; K = 768;  N = 768;  xt = b1 % 12; yt = b1 / 12; }
        else if (b < 1152) { int b1 = b - 576;  in = w_fc;   outp = wfc_t;   K = 768;  N = 3072; xt = b1 % 48; yt = b1 / 48; }
        else               { int b1 = b - 1152; in = w_out;  outp = wout_t;  K = 3072; N = 768;  xt = b1 % 12; yt = b1 / 12; }
        float (*sm)[65] = (float(*)[65])smem;
        int n0 = xt * 64, k0 = yt * 64;
        int rr = t >> 4, cc = (t & 15) * 4;
        #pragma unroll
        for (int it = 0; it < 4; it++) {
            int kr = it * 16 + rr;
            float4 v = *(const float4*)&in[(size_t)(k0 + kr) * N + n0 + cc];
            sm[kr][cc + 0] = v.x; sm[kr][cc + 1] = v.y;
            sm[kr][cc + 2] = v.z; sm[kr][cc + 3] = v.w;
        }
        __syncthreads();
        #pragma unroll
        for (int it = 0; it < 4; it++) {
            int nr = it * 16 + rr;
            b4 o;
            #pragma unroll
            for (int j = 0; j < 4; j++) o.v[j] = __float2bfloat16(sm[cc + j][nr]);
            *(b4*)&outp[(size_t)(n0 + nr) * K + k0 + cc] = o;
        }
    }
}

// ---------------------------------------------------------------------------
// LayerNorm (LN2): one block per row, 256 threads; f32 in -> bf16 out.
// ---------------------------------------------------------------------------
__global__ __launch_bounds__(256) void ln_kernel(const float* __restrict__ x,
                                                 const float* __restrict__ g,
                                                 const float* __restrict__ bta,
                                                 bf16* __restrict__ out) {
    int row = blockIdx.x;
    int t = threadIdx.x;
    const float* xr = x + (size_t)row * DD;
    float v0 = xr[t], v1 = xr[t + 256], v2 = xr[t + 512];
    float s = v0 + v1 + v2;
    float s2 = v0 * v0 + v1 * v1 + v2 * v2;
    #pragma unroll
    for (int off = 32; off > 0; off >>= 1) {
        s  += __shfl_xor(s,  off, 64);
        s2 += __shfl_xor(s2, off, 64);
    }
    __shared__ float ls[4], ls2[4];
    if ((t & 63) == 0) { ls[t >> 6] = s; ls2[t >> 6] = s2; }
    __syncthreads();
    s  = ls[0] + ls[1] + ls[2] + ls[3];
    s2 = ls2[0] + ls2[1] + ls2[2] + ls2[3];
    float mu  = s * (1.0f / DD);
    float var = s2 * (1.0f / DD) - mu * mu;
    float r = rsqrtf(var + EPS_LN);
    bf16* orow = out + (size_t)row * DD;
    orow[t]       = __float2bfloat16((v0 - mu) * r * g[t]       + bta[t]);
    orow[t + 256] = __float2bfloat16((v1 - mu) * r * g[t + 256] + bta[t + 256]);
    orow[t + 512] = __float2bfloat16((v2 - mu) * r * g[t + 512] + bta[t + 512]);
}

// ---------------------------------------------------------------------------
// 4x4 supertile swizzle.
// ---------------------------------------------------------------------------
__device__ inline void swizzle44(int bid, int nx4, int& bx, int& by) {
    int g = bid >> 4, r = bid & 15;
    bx = (g % nx4) * 4 + (r & 3);
    by = (g / nx4) * 4 + (r >> 2);
}

__device__ inline float gelu_tanh(float x) {
    float x3 = x * x * x;
    float u = 0.7978845608028654f * (x + 0.044715f * x3);
    return 0.5f * x * (1.0f + tanhf(u));
}

// ---------------------------------------------------------------------------
// TM=64 x TN=64, BK=128 GEMM — r17-proven swizzled gload_lds.
// SQMODE (qkv only): q/k head tiles reduce ||head||^2/16 into sqbuf.
// ---------------------------------------------------------------------------
template <int ACT, int HAS_RES, int OUT_BF16, int SQMODE>
__global__ __launch_bounds__(256) void gemm_k128(const bf16* __restrict__ A,
                                                 const bf16* __restrict__ BT,
                                                 const float* __restrict__ bias,
                                                 const float* __restrict__ res,
                                                 void* __restrict__ Cout,
                                                 int N, int K, int nx4,
                                                 float* __restrict__ sqbuf) {
    __shared__ bf16 Asl[64][128];
    __shared__ bf16 Bsl[64][128];
    int bx, by;
    swizzle44(blockIdx.x, nx4, bx, by);
    int tid = threadIdx.x;
    int m0 = by * 64, n0 = bx * 64;
    int wave = tid >> 6, lane = tid & 63;
    int qm = lane & 15, quad = lane >> 4;
    int srow = lane >> 4;
    int chnk = lane & 15;
    int sce = (chnk ^ srow) * 8;          // i even
    int sco = (chnk ^ (srow + 4)) * 8;    // i odd
    const bf16* ag = A  + (size_t)(m0 + wave * 16 + srow) * K;
    const bf16* bg = BT + (size_t)(n0 + wave * 16 + srow) * K;
    int xr = (qm & 7) << 3;               // read-side XOR (elements)

    v4f acc[4] = {{0.f,0.f,0.f,0.f},{0.f,0.f,0.f,0.f},{0.f,0.f,0.f,0.f},{0.f,0.f,0.f,0.f}};

    for (int k0 = 0; k0 < K; k0 += 128) {
        __syncthreads();
        #pragma unroll
        for (int i = 0; i < 4; i++) {
            int sc = (i & 1) ? sco : sce;
            gload16(ag + (size_t)(4 * i) * K + k0 + sc, &Asl[wave * 16 + 4 * i][0]);
            gload16(bg + (size_t)(4 * i) * K + k0 + sc, &Bsl[wave * 16 + 4 * i][0]);
        }
        __syncthreads();
        #pragma unroll
        for (int kc = 0; kc < 4; kc++) {
            v8s a = *(const v8s*)&Asl[wave * 16 + qm][(kc * 32 + quad * 8) ^ xr];
            #pragma unroll
            for (int n = 0; n < 4; n++) {
                v8s b = *(const v8s*)&Bsl[n * 16 + qm][(kc * 32 + quad * 8) ^ xr];
                acc[n] = __builtin_amdgcn_mfma_f32_16x16x32_bf16(a, b, acc[n], 0, 0, 0);
            }
        }
    }

    int col_l = lane & 15;
    if (SQMODE && n0 < 1536) {
        int hidx = n0 >> 6;               // q heads 0..11, k heads 12..23
        #pragma unroll
        for (int r = 0; r < 4; r++) {
            float hsq = 0.f;
            #pragma unroll
            for (int t2 = 0; t2 < 4; t2++) {
                float v = acc[t2][r] + bias[n0 + t2 * 16 + col_l];
                hsq += v * v;
            }
            hsq += __shfl_xor(hsq, 1, 64); hsq += __shfl_xor(hsq, 2, 64);
            hsq += __shfl_xor(hsq, 4, 64); hsq += __shfl_xor(hsq, 8, 64);
            if (col_l == 0) {
                int row = m0 + wave * 16 + quad * 4 + r;
                sqbuf[row * 24 + hidx] = hsq * (1.0f / 16.0f);
            }
        }
        return;
    }
    #pragma unroll
    for (int t2 = 0; t2 < 4; t2++) {
        int col = n0 + t2 * 16 + col_l;
        float bcol = bias[col];
        #pragma unroll
        for (int r = 0; r < 4; r++) {
            int row = m0 + wave * 16 + quad * 4 + r;
            float v = acc[t2][r] + bcol;
            if (ACT == 1) v = gelu_tanh(v);
            if (HAS_RES) v += res[(size_t)row * N + col];
            if (OUT_BF16) ((bf16*)Cout)[(size_t)row * N + col] = __float2bfloat16(v);
            else          ((float*)Cout)[(size_t)row * N + col] = v;
        }
    }
}

// ---------------------------------------------------------------------------
// TM=32 x TN=64, BK=128 GEMM (proj/out, N=768) — gload_lds + XOR swizzle.
// ---------------------------------------------------------------------------
template <int ACT, int HAS_RES, int OUT_BF16>
__global__ __launch_bounds__(256) void gemm_m32_k128(const bf16* __restrict__ A,
                                                     const bf16* __restrict__ BT,
                                                     const float* __restrict__ bias,
                                                     const float* __restrict__ res,
                                                     void* __restrict__ Cout,
                                                     int N, int K, int nx4) {
    __shared__ bf16 Asl[32][128];
    __shared__ bf16 Bsl[64][128];
    int bx, by;
    swizzle44(blockIdx.x, nx4, bx, by);
    int tid = threadIdx.x;
    int m0 = by * 32, n0 = bx * 64;
    int wave = tid >> 6, lane = tid & 63;
    int qm = lane & 15, quad = lane >> 4;
    int rowh = (wave & 1) * 16;
    int colh = (wave >> 1) * 32;
    int srow = lane >> 4;
    int chnk = lane & 15;
    int sce = (chnk ^ srow) * 8;          // i even
    int sco = (chnk ^ (srow + 4)) * 8;    // i odd
    const bf16* ag = A  + (size_t)(m0 + wave * 8  + srow) * K;
    const bf16* bg = BT + (size_t)(n0 + wave * 16 + srow) * K;
    int xr = (qm & 7) << 3;

    v4f acc[2] = {{0.f,0.f,0.f,0.f},{0.f,0.f,0.f,0.f}};

    for (int k0 = 0; k0 < K; k0 += 128) {
        __syncthreads();
        #pragma unroll
        for (int i = 0; i < 2; i++) {
            int sc = (i & 1) ? sco : sce;
            gload16(ag + (size_t)(4 * i) * K + k0 + sc, &Asl[wave * 8 + 4 * i][0]);
        }
        #pragma unroll
        for (int i = 0; i < 4; i++) {
            int sc = (i & 1) ? sco : sce;
            gload16(bg + (size_t)(4 * i) * K + k0 + sc, &Bsl[wave * 16 + 4 * i][0]);
        }
        __syncthreads();
        #pragma unroll
        for (int kc = 0; kc < 4; kc++) {
            v8s a  = *(const v8s*)&Asl[rowh + qm][(kc * 32 + quad * 8) ^ xr];
            v8s b0 = *(const v8s*)&Bsl[colh + qm][(kc * 32 + quad * 8) ^ xr];
            v8s b1 = *(const v8s*)&Bsl[colh + 16 + qm][(kc * 32 + quad * 8) ^ xr];
            acc[0] = __builtin_amdgcn_mfma_f32_16x16x32_bf16(a, b0, acc[0], 0, 0, 0);
            acc[1] = __builtin_amdgcn_mfma_f32_16x16x32_bf16(a, b1, acc[1], 0, 0, 0);
        }
    }

    #pragma unroll
    for (int ct = 0; ct < 2; ct++) {
        int col = n0 + colh + ct * 16 + qm;
        float bcol = bias[col];
        #pragma unroll
        for (int r = 0; r < 4; r++) {
            int row = m0 + rowh + quad * 4 + r;
            float v = acc[ct][r] + bcol;
            if (ACT == 1) v = gelu_tanh(v);
            if (HAS_RES) v += res[(size_t)row * N + col];
            if (OUT_BF16) ((bf16*)Cout)[(size_t)row * N + col] = __float2bfloat16(v);
            else          ((float*)Cout)[(size_t)row * N + col] = v;
        }
    }
}

// ---------------------------------------------------------------------------
// Scan phase 1 (MFMA): phi(k) from proj_k + precomputed sq.
// StateT[d][m] = V^T @ phik ; Sk[m] = col-sum(phik).
// ---------------------------------------------------------------------------
__global__ __launch_bounds__(256) void scan_sums_mfma(const bf16* __restrict__ qkvp,
                                                      const float* __restrict__ sqbuf,
                                                      float* __restrict__ StateT,
                                                      float* __restrict__ Sk) {
    int c = blockIdx.x, h = blockIdx.y, b = blockIdx.z;
    int bh = b * HH + h;
    int t = threadIdx.x;
    __shared__ bf16 vt[64][72];   // V^T[d][s]
    __shared__ bf16 kt[64][72];   // phik^T[m][s]
    int sr = t >> 4, cq = (t & 15) * 4;
    #pragma unroll
    for (int i = 0; i < 4; i++) {
        int s = sr + 16 * i;
        size_t grow = (size_t)b * SS + c * CC + s;
        size_t rowg = grow * NQ + h * DHH;
        b4 vv = *(const b4*)&qkvp[rowg + VOFF  + cq];
        b4 kp = *(const b4*)&qkvp[rowg + PKOFF + cq];   // proj_k
        float sq = sqbuf[grow * 24 + 12 + h];
        #pragma unroll
        for (int j = 0; j < 4; j++) {
            vt[cq + j][s] = vv.v[j];
            kt[cq + j][s] = __float2bfloat16(
                __expf(__bfloat162float(kp.v[j]) - sq) * 0.125f + EPS_PHI);
        }
    }
    __syncthreads();
    int wave = t >> 6, lane = t & 63, qm = lane & 15, quad = lane >> 4;
    v4f acc[4] = {{0.f,0.f,0.f,0.f},{0.f,0.f,0.f,0.f},{0.f,0.f,0.f,0.f},{0.f,0.f,0.f,0.f}};
    #pragma unroll
    for (int k0 = 0; k0 < 64; k0 += 32) {
        v8s a = *(const v8s*)&vt[wave * 16 + qm][k0 + quad * 8];
        #pragma unroll
        for (int n = 0; n < 4; n++) {
            v8s bb = *(const v8s*)&kt[n * 16 + qm][k0 + quad * 8];
            acc[n] = __builtin_amdgcn_mfma_f32_16x16x32_bf16(a, bb, acc[n], 0, 0, 0);
        }
    }
    float* dst = StateT + ((size_t)bh * NC + c) * 4096;
    int col_l = lane & 15;
    #pragma unroll
    for (int n = 0; n < 4; n++)
        #pragma unroll
        for (int r = 0; r < 4; r++) {
            int d = wave * 16 + quad * 4 + r;
            dst[d * 64 + n * 16 + col_l] = acc[n][r];
        }
    {   // parallel col-sum: 4 threads per m
        int m = t >> 2, j = t & 3;
        float sum = 0.f;
        #pragma unroll
        for (int i2 = 0; i2 < 16; i2++) sum += __bfloat162float(kt[m][j * 16 + i2]);
        sum += __shfl_xor(sum, 1, 64);
        sum += __shfl_xor(sum, 2, 64);
        if (j == 0) Sk[((size_t)bh * NC + c) * 64 + m] = sum;
    }
}

// ---------------------------------------------------------------------------
// Scan phase 2: in-place EXCLUSIVE prefix over chunks.
// ---------------------------------------------------------------------------
__global__ __launch_bounds__(256) void scan_prefix_kernel(float* __restrict__ Skv,
                                                          float* __restrict__ Sk) {
    int bh = blockIdx.y;
    int t = blockIdx.x * 256 + threadIdx.x;
    size_t base = (size_t)bh * NC * 4096 + t;
    float acc = 0.f;
    for (int c = 0; c < NC; c++) {
        float v = Skv[base + (size_t)c * 4096];
        Skv[base + (size_t)c * 4096] = acc;
        acc += v;
    }
    if (blockIdx.x == 0 && threadIdx.x < 64) {
        size_t b2 = (size_t)bh * NC * 64 + threadIdx.x;
        float a2 = 0.f;
        for (int c = 0; c < NC; c++) {
            float v = Sk[b2 + (size_t)c * 64];
            Sk[b2 + (size_t)c * 64] = a2;
            a2 += v;
        }
    }
}

// ---------------------------------------------------------------------------
// Scan phase 3 (MFMA): phi from proj + precomputed sq; den via VALU.
// acc = phiq@StateT^T + P@V; attn = acc/den.
// ---------------------------------------------------------------------------
__global__ __launch_bounds__(256) void scan_chunk_mfma(const bf16* __restrict__ qkvp,
                                                       const float* __restrict__ sqbuf,
                                                       const float* __restrict__ StateT,
                                                       const float* __restrict__ SkPre,
                                                       bf16* __restrict__ attn) {
    int c = blockIdx.x, h = blockIdx.y, b = blockIdx.z;
    int bh = b * HH + h;
    int t = threadIdx.x;
    __shared__ bf16 qs[64][72];
    __shared__ bf16 ks[64][72];
    __shared__ bf16 vt[64][72];
    __shared__ bf16 stl[64][72];
    __shared__ bf16 P[64][72];
    int sr = t >> 4, cq = (t & 15) * 4;
    const float* stg = StateT + ((size_t)bh * NC + c) * 4096;
    #pragma unroll
    for (int i = 0; i < 4; i++) {
        int s = sr + 16 * i;
        size_t grow = (size_t)b * SS + c * CC + s;
        size_t rowg = grow * NQ + h * DHH;
        b4 qp = *(const b4*)&qkvp[rowg + PQOFF + cq];   // proj_q
        b4 kp = *(const b4*)&qkvp[rowg + PKOFF + cq];   // proj_k
        b4 vv = *(const b4*)&qkvp[rowg + VOFF  + cq];
        float4 sv = *(const float4*)&stg[s * 64 + cq];
        float sqq = sqbuf[grow * 24 + h];
        float sqk = sqbuf[grow * 24 + 12 + h];
        #pragma unroll
        for (int j = 0; j < 4; j++) {
            qs[s][cq + j] = __float2bfloat16(
                __expf(__bfloat162float(qp.v[j]) - sqq) * 0.125f + EPS_PHI);
            ks[s][cq + j] = __float2bfloat16(
                __expf(__bfloat162float(kp.v[j]) - sqk) * 0.125f + EPS_PHI);
            vt[cq + j][s] = vv.v[j];
        }
        stl[s][cq + 0] = __float2bfloat16(sv.x);
        stl[s][cq + 1] = __float2bfloat16(sv.y);
        stl[s][cq + 2] = __float2bfloat16(sv.z);
        stl[s][cq + 3] = __float2bfloat16(sv.w);
    }
    __syncthreads();
    int wave = t >> 6, lane = t & 63, qm = lane & 15, quad = lane >> 4;
    int col_l = lane & 15;
    int row0 = wave * 16;

    v4f a1[4] = {{0.f,0.f,0.f,0.f},{0.f,0.f,0.f,0.f},{0.f,0.f,0.f,0.f},{0.f,0.f,0.f,0.f}};
    #pragma unroll
    for (int k0 = 0; k0 < 64; k0 += 32) {
        v8s a = *(const v8s*)&qs[row0 + qm][k0 + quad * 8];
        #pragma unroll
        for (int n = 0; n < 4; n++) {
            v8s bb = *(const v8s*)&ks[n * 16 + qm][k0 + quad * 8];
            a1[n] = __builtin_amdgcn_mfma_f32_16x16x32_bf16(a, bb, a1[n], 0, 0, 0);
        }
    }
    float denl[4] = {0.f, 0.f, 0.f, 0.f};
    #pragma unroll
    for (int n = 0; n < 4; n++)
        #pragma unroll
        for (int r = 0; r < 4; r++) {
            int row = row0 + quad * 4 + r;
            int col = n * 16 + col_l;
            float v = (col <= row) ? a1[n][r] : 0.f;
            P[row][col] = __float2bfloat16(v);
            denl[r] += v;
        }
    {   // + phiq . SkPre (cross-chunk part); lane handles m = qm*4..qm*4+3
        const float* skp = SkPre + ((size_t)bh * NC + c) * 64;
        float4 sk4 = *(const float4*)&skp[qm * 4];
        #pragma unroll
        for (int r = 0; r < 4; r++) {
            int row = row0 + quad * 4 + r;
            b4 qv = *(const b4*)&qs[row][qm * 4];
            denl[r] += __bfloat162float(qv.v[0]) * sk4.x
                     + __bfloat162float(qv.v[1]) * sk4.y
                     + __bfloat162float(qv.v[2]) * sk4.z
                     + __bfloat162float(qv.v[3]) * sk4.w;
        }
    }
    #pragma unroll
    for (int r = 0; r < 4; r++) {
        denl[r] += __shfl_xor(denl[r], 1, 64);
        denl[r] += __shfl_xor(denl[r], 2, 64);
        denl[r] += __shfl_xor(denl[r], 4, 64);
        denl[r] += __shfl_xor(denl[r], 8, 64);
    }
    v4f acc[4] = {{0.f,0.f,0.f,0.f},{0.f,0.f,0.f,0.f},{0.f,0.f,0.f,0.f},{0.f,0.f,0.f,0.f}};
    #pragma unroll
    for (int k0 = 0; k0 < 64; k0 += 32) {
        v8s aq = *(const v8s*)&qs[row0 + qm][k0 + quad * 8];
        v8s ap = *(const v8s*)&P [row0 + qm][k0 + quad * 8];
        #pragma unroll
        for (int n = 0; n < 4; n++) {
            v8s b1 = *(const v8s*)&stl[n * 16 + qm][k0 + quad * 8];
            v8s b2 = *(const v8s*)&vt [n * 16 + qm][k0 + quad * 8];
            acc[n] = __builtin_amdgcn_mfma_f32_16x16x32_bf16(aq, b1, acc[n], 0, 0, 0);
            acc[n] = __builtin_amdgcn_mfma_f32_16x16x32_bf16(ap, b2, acc[n], 0, 0, 0);
        }
    }
    #pragma unroll
    for (int n = 0; n < 4; n++)
        #pragma unroll
        for (int r = 0; r < 4; r++) {
            int srow = row0 + quad * 4 + r;
            int d = n * 16 + col_l;
            attn[((size_t)b * SS + c * CC + srow) * DD + h * DHH + d] =
                __float2bfloat16(acc[n][r] / denl[r]);
        }
}

// ---------------------------------------------------------------------------
extern "C" void kernel_launch(void* const* d_in, const int* in_sizes, int n_in,
                              void* d_out, int out_size, void* d_ws, size_t ws_size,
                              hipStream_t stream) {
    const float* x      = (const float*)d_in[0];
    const float* ln1_g  = (const float*)d_in[1];
    const float* ln1_b  = (const float*)d_in[2];
    const float* w_attn = (const float*)d_in[3];
    const float* b_attn = (const float*)d_in[4];
    const float* w_feat = (const float*)d_in[5];
    const float* w_proj = (const float*)d_in[6];
    const float* b_proj = (const float*)d_in[7];
    const float* ln2_g  = (const float*)d_in[8];
    const float* ln2_b  = (const float*)d_in[9];
    const float* w_fc   = (const float*)d_in[10];
    const float* b_fc   = (const float*)d_in[11];
    const float* w_out  = (const float*)d_in[12];
    const float* b_out  = (const float*)d_in[13];
    float* out = (float*)d_out;

    // f32 region
    float* ws = (float*)d_ws;
    size_t off = 0;
    float* buf_x1   = ws + off; off += (size_t)BS * DD;            // 1.57M f32
    float* buf_sk   = ws + off; off += (size_t)BB * HH * NC * MM;  // 24.6K
    float* bias_ext = ws + off; off += NQ;
    float* buf_sq   = ws + off; off += (size_t)BS * 24;            // ||head||^2/16
    // bf16 region (16B-aligned: preceding counts are multiples of 4)
    bf16* wb = (bf16*)(ws + off);
    size_t boff = 0;
    bf16* buf_qkvp    = wb + boff; boff += (size_t)BS * NQ;        // 7.86M bf16
    bf16* buf_a_bf    = wb + boff; boff += (size_t)BS * DD;
    bf16* buf_attn_bf = wb + boff; boff += (size_t)BS * DD;
    bf16* wext_t      = wb + boff; boff += (size_t)NQ * DD;
    bf16* wproj_t     = wb + boff; boff += (size_t)DD * DD;
    bf16* wfc_t       = wb + boff; boff += (size_t)DFF * DD;
    bf16* wout_t      = wb + boff; boff += (size_t)DD * DFF;
    // Aliases: StateT (1.57M f32) over buf_x1 (x1 written after scan);
    //          fc bf16 (6.29M) over buf_qkvp head (qkvp dead after scan).
    float* buf_skv   = buf_x1;
    bf16*  buf_fc_bf = buf_qkvp;

    // 0a) FAVOR+ fused cols + bias (own dispatch: 33.3KB LDS only here)
    feat_kernel<<<289, 256, 0, stream>>>(w_attn, b_attn, w_feat, wext_t, bias_ext);
    // 0b) LN1 + transposes (16.9KB LDS -> 8 blocks/CU)
    prep_main<<<3776, 256, 0, stream>>>(x, ln1_g, ln1_b,
                                        w_attn, w_proj, w_fc, w_out,
                                        buf_a_bf, wext_t, wproj_t, wfc_t, wout_t);
    // 1) [qkv | proj] = a @ W_ext + bias_ext; q/k head tiles -> sq only
    gemm_k128<0, 0, 1, 1><<<1920, 256, 0, stream>>>(
        buf_a_bf, wext_t, bias_ext, nullptr, buf_qkvp, NQ, DD, 15, buf_sq);
    // 2a) per-chunk sums (MFMA, phi-k from sq)
    scan_sums_mfma<<<dim3(NC, HH, BB), 256, 0, stream>>>(buf_qkvp, buf_sq, buf_skv, buf_sk);
    // 2b) exclusive prefix over chunks
    scan_prefix_kernel<<<dim3(4096 / 256, BB * HH), 256, 0, stream>>>(buf_skv, buf_sk);
    // 2c) per-chunk masked-MFMA scan -> attn
    scan_chunk_mfma<<<dim3(NC, HH, BB), 256, 0, stream>>>(
        buf_qkvp, buf_sq, buf_skv, buf_sk, buf_attn_bf);
    // 3) x1 = x + attn @ w_proj + b_proj
    gemm_m32_k128<0, 1, 0><<<768, 256, 0, stream>>>(
        buf_attn_bf, wproj_t, b_proj, x, buf_x1, DD, DD, 3);
    // 4) m = LN2(x1) -> bf16
    ln_kernel<<<BS, 256, 0, stream>>>(buf_x1, ln2_g, ln2_b, buf_a_bf);
    // 5) fc = gelu(m @ w_fc + b_fc) -> bf16
    gemm_k128<1, 0, 1, 0><<<1536, 256, 0, stream>>>(
        buf_a_bf, wfc_t, b_fc, nullptr, buf_fc_bf, DFF, DD, 12, nullptr);
    // 6) out = x1 + fc @ w_out + b_out
    gemm_m32_k128<0, 1, 0><<<768, 256, 0, stream>>>(
        buf_fc_bf, wout_t, b_out, buf_x1, out, DD, DFF, 3);
}